// Round 2
// baseline (1845.456 us; speedup 1.0000x reference)
//
#include <hip/hip_runtime.h>
#include <cmath>

#define BC 2048          // B*W sequences
#define S_LEN 8192
#define MODES 42
#define HTOT 8232        // packed high-band pyramid length per sequence

// db6 reconstruction low-pass (from reference)
static constexpr float C_LO[12] = {
  0.11154074335008017f, 0.4946238903983854f, 0.7511339080215775f,
  0.3152503517092432f, -0.22626469396516913f, -0.12976686756709563f,
  0.09750160558707936f, 0.02752286553001629f, -0.031582039318031156f,
  0.0005538422009938016f, 0.004777257511010651f, -0.00107730108499558f };

__device__ __forceinline__ float rec_lo_c(int k){ return C_LO[k]; }
__device__ __forceinline__ float rec_hi_c(int k){ float v = C_LO[11-k]; return (k&1)? -v : v; }
__device__ __forceinline__ float dec_lo_c(int k){ return C_LO[11-k]; }
__device__ __forceinline__ float dec_hi_c(int k){ float v = C_LO[k];    return (k&1)?  v : -v; }

__device__ __forceinline__ float gelu_f(float x){
  return 0.5f * x * (1.0f + erff(x * 0.70710678118654752440f));
}

// ---------------------------------------------------------------- fc0
// v[b,c,s] = x[b,s]*w[0,c] + grid[s]*w[1,c] + b[c];  v layout [B*W][S]
__global__ __launch_bounds__(256) void fc0_kernel(
    const float* __restrict__ x, const float* __restrict__ w,
    const float* __restrict__ bias, float* __restrict__ v)
{
  int p = blockIdx.x * 256 + threadIdx.x;   // p = b*8192 + s
  int b = p >> 13, s = p & 8191;
  float xv = x[p];
  float g  = (float)s * (1.0f / 8191.0f);
  for (int c = 0; c < 64; ++c) {
    v[((size_t)(b * 64 + c)) * S_LEN + s] = xv * w[c] + g * w[64 + c] + bias[c];
  }
}

// ---------------------------------------------------------------- DWT (all 8 levels, block per sequence)
__global__ __launch_bounds__(256) void dwt_all(
    const float* __restrict__ vin,   // [2048][8192]
    float* __restrict__ highs,       // [2048][8232]
    float* __restrict__ yl)          // [2048][42]
{
  __shared__ float4 A4[2048];
  __shared__ float  B[4104];
  float* A = (float*)A4;
  int seq = blockIdx.x;

  const float4* s4 = (const float4*)(vin + (size_t)seq * S_LEN);
  for (int i = threadIdx.x; i < 2048; i += 256) A4[i] = s4[i];
  __syncthreads();

  const int ns[9]  = {8192, 4101, 2056, 1033, 522, 266, 138, 74, 42};
  const int off[8] = {0, 4101, 6157, 7190, 7712, 7978, 8116, 8190};

  #pragma unroll
  for (int l = 0; l < 8; ++l) {
    int n = ns[l], outlen = ns[l + 1];
    const float* in = (l & 1) ? B : A;
    float* out      = (l & 1) ? A : B;
    int pl = (2 * (outlen - 1) - n + 12) / 2;
    float* hg = highs + (size_t)seq * HTOT + off[l];
    for (int m = threadIdx.x; m < outlen; m += 256) {
      float alo = 0.f, ahi = 0.f;
      #pragma unroll
      for (int k = 0; k < 12; ++k) {
        int t = 2 * m + k - pl;
        t = (t < 0) ? (-1 - t) : t;
        t = (t >= n) ? (2 * n - 1 - t) : t;
        float xv = in[t];
        alo += xv * rec_lo_c(k);
        ahi += xv * rec_hi_c(k);
      }
      out[m] = alo;
      hg[m]  = ahi;
    }
    __syncthreads();
  }
  // final lo (42) ends in A
  for (int m = threadIdx.x; m < MODES; m += 256) yl[seq * MODES + m] = A[m];
}

// ---------------------------------------------------------------- coarse-band channel mix
// out[(b*64+o)*42+x] = sum_i in[(b*64+i)*in_stride + x] * w[(i*64+o)*42 + x]
__global__ __launch_bounds__(256) void mix42(
    const float* __restrict__ in, int in_stride,
    const float* __restrict__ w, float* __restrict__ out)
{
  int idx = blockIdx.x * 256 + threadIdx.x;
  if (idx >= 32 * 64 * MODES) return;
  int xx = idx % MODES;
  int o  = (idx / MODES) % 64;
  int b  = idx / (MODES * 64);
  float acc = 0.f;
  for (int i = 0; i < 64; ++i)
    acc += in[((size_t)(b * 64 + i)) * in_stride + xx] * w[(i * 64 + o) * MODES + xx];
  out[(b * 64 + o) * MODES + xx] = acc;
}

// ---------------------------------------------------------------- IDWT (all 8 levels, block per sequence)
__global__ __launch_bounds__(256) void idwt_all(
    const float* __restrict__ yl_m,   // [2048][42]
    const float* __restrict__ yh_m,   // [2048][42]
    const float* __restrict__ highs,  // [2048][8232]
    float* __restrict__ x1)           // [2048][8192]
{
  __shared__ float b0[4104], b1[4104];
  int seq = blockIdx.x;

  const int hlen[8] = {42, 74, 138, 266, 522, 1033, 2056, 4101};
  const int hoff[8] = {8190, 8116, 7978, 7712, 7190, 6157, 4101, 0};

  #pragma unroll
  for (int s = 0; s < 8; ++s) {
    int len  = hlen[s];
    int outn = 2 * len - 10;
    const float* h     = (s == 0) ? (yh_m + (size_t)seq * MODES)
                                  : (highs + (size_t)seq * HTOT + hoff[s]);
    const float* lo_in = (s == 0) ? (yl_m + (size_t)seq * MODES)
                                  : ((s & 1) ? b0 : b1);
    float* out = (s == 7) ? (x1 + (size_t)seq * S_LEN) : ((s & 1) ? b1 : b0);
    for (int m = threadIdx.x; m < outn; m += 256) {
      float acc = 0.f;
      #pragma unroll
      for (int k = 0; k < 12; ++k) {
        int j = m + k - 1;
        if (j & 1) continue;          // only even dilated positions carry data
        int t = j >> 1;
        if (t < len) acc += lo_in[t] * dec_lo_c(k) + h[t] * dec_hi_c(k);
      }
      out[m] = acc;
    }
    __syncthreads();
  }
}

// ---------------------------------------------------------------- per-layer pointwise: v = gelu?(x1 + v@cw + cb)
__global__ __launch_bounds__(256) void layer_pw(
    const float* __restrict__ x1, float* __restrict__ v,
    const float* __restrict__ cw, const float* __restrict__ cb, int do_gelu)
{
  __shared__ float vt[64][65];
  int b  = blockIdx.x >> 7;            // 128 s-tiles per batch
  int s0 = (blockIdx.x & 127) << 6;
  int t  = threadIdx.x;
  int sl = t & 63;
  int wv = __builtin_amdgcn_readfirstlane(t >> 6);   // wave id (uniform)

  for (int r = 0; r < 16; ++r) {
    int idx = t + 256 * r;
    int i = idx >> 6, s = idx & 63;
    vt[i][s] = v[((size_t)(b * 64 + i)) * S_LEN + s0 + s];
  }
  __syncthreads();

  float vr[64];
  #pragma unroll
  for (int i = 0; i < 64; ++i) vr[i] = vt[i][sl];

  for (int r = 0; r < 16; ++r) {
    int o = wv * 16 + r;
    float acc = cb[o];
    #pragma unroll
    for (int i = 0; i < 64; ++i) acc += vr[i] * cw[i * 64 + o];   // cw: uniform -> s_load
    float y = x1[((size_t)(b * 64 + o)) * S_LEN + s0 + sl] + acc;
    if (do_gelu) y = gelu_f(y);
    v[((size_t)(b * 64 + o)) * S_LEN + s0 + sl] = y;
  }
}

// ---------------------------------------------------------------- head: out = gelu(v^T @ fc1 + b1) @ fc2 + b2
__global__ __launch_bounds__(256) void head_kernel(
    const float* __restrict__ v, const float* __restrict__ fc1w,
    const float* __restrict__ fc1b, const float* __restrict__ fc2w,
    const float* __restrict__ fc2b, float* __restrict__ out)
{
  int p = blockIdx.x * 256 + threadIdx.x;   // p = b*8192 + s
  int b = p >> 13, s = p & 8191;
  float vr[64];
  #pragma unroll
  for (int c = 0; c < 64; ++c) vr[c] = v[((size_t)(b * 64 + c)) * S_LEN + s];
  float res = fc2b[0];
  for (int j = 0; j < 128; ++j) {
    float d = fc1b[j];
    #pragma unroll
    for (int c = 0; c < 64; ++c) d += vr[c] * fc1w[c * 128 + j];   // uniform -> s_load
    res += fc2w[j] * gelu_f(d);
  }
  out[p] = res;
}

// ----------------------------------------------------------------
extern "C" void kernel_launch(void* const* d_in, const int* in_sizes, int n_in,
                              void* d_out, int out_size, void* d_ws, size_t ws_size,
                              hipStream_t stream) {
  const float* x    = (const float*)d_in[0];
  const float* fc0w = (const float*)d_in[1];
  const float* fc0b = (const float*)d_in[2];
  const float* w1   = (const float*)d_in[3];
  const float* w2   = (const float*)d_in[4];
  const float* cw   = (const float*)d_in[5];
  const float* cb   = (const float*)d_in[6];
  const float* fc1w = (const float*)d_in[7];
  const float* fc1b = (const float*)d_in[8];
  const float* fc2w = (const float*)d_in[9];
  const float* fc2b = (const float*)d_in[10];
  float* out = (float*)d_out;

  float* ws     = (float*)d_ws;
  float* v      = ws;
  float* x1     = v      + (size_t)BC * S_LEN;
  float* highs  = x1     + (size_t)BC * S_LEN;
  float* yl_raw = highs  + (size_t)BC * HTOT;
  float* yl_m   = yl_raw + (size_t)BC * MODES;
  float* yh_m   = yl_m   + (size_t)BC * MODES;
  size_t needed = (size_t)((yh_m + (size_t)BC * MODES) - ws) * sizeof(float);
  if (ws_size < needed) return;   // insufficient workspace — fail visibly

  fc0_kernel<<<1024, 256, 0, stream>>>(x, fc0w, fc0b, v);

  for (int i = 0; i < 4; ++i) {
    dwt_all<<<BC, 256, 0, stream>>>(v, highs, yl_raw);
    mix42<<<336, 256, 0, stream>>>(yl_raw, MODES, w1 + (size_t)i * 64 * 64 * MODES, yl_m);
    mix42<<<336, 256, 0, stream>>>(highs + 8190, HTOT, w2 + (size_t)i * 64 * 64 * MODES, yh_m);
    idwt_all<<<BC, 256, 0, stream>>>(yl_m, yh_m, highs, x1);
    layer_pw<<<4096, 256, 0, stream>>>(x1, v, cw + i * 4096, cb + i * 64, (i < 3) ? 1 : 0);
  }

  head_kernel<<<1024, 256, 0, stream>>>(v, fc1w, fc1b, fc2w, fc2b, out);
}

// Round 3
// 847.371 us; speedup vs baseline: 2.1779x; 2.1779x over previous
//
#include <hip/hip_runtime.h>
#include <cmath>

#define BC 2048          // B*W sequences
#define S_LEN 8192
#define MODES 42
#define HTOT 8232        // packed high-band pyramid: offs {0,4101,6157,7190,7712,7978,8116,8190}

static constexpr float C_LO[12] = {
  0.11154074335008017f, 0.4946238903983854f, 0.7511339080215775f,
  0.3152503517092432f, -0.22626469396516913f, -0.12976686756709563f,
  0.09750160558707936f, 0.02752286553001629f, -0.031582039318031156f,
  0.0005538422009938016f, 0.004777257511010651f, -0.00107730108499558f };

__device__ __forceinline__ float rec_lo_c(int k){ return C_LO[k]; }
__device__ __forceinline__ float rec_hi_c(int k){ float v = C_LO[11-k]; return (k&1)? -v : v; }
__device__ __forceinline__ float dec_lo_c(int k){ return C_LO[11-k]; }
__device__ __forceinline__ float dec_hi_c(int k){ float v = C_LO[k];    return (k&1)?  v : -v; }

__device__ __forceinline__ float gelu_f(float x){
  return 0.5f * x * (1.0f + erff(x * 0.70710678118654752440f));
}

__device__ __forceinline__ int reflect_i(int t, int n){
  t = (t < 0) ? (-1 - t) : t;
  t = (t >= n) ? (2 * n - 1 - t) : t;
  return t;
}

// ---------------------------------------------------------------- fc0
__global__ __launch_bounds__(256) void fc0_kernel(
    const float* __restrict__ x, const float* __restrict__ w,
    const float* __restrict__ bias, float* __restrict__ v)
{
  int p = blockIdx.x * 256 + threadIdx.x;   // p = b*8192 + s
  int b = p >> 13, s = p & 8191;
  float xv = x[p];
  float g  = (float)s * (1.0f / 8191.0f);
  for (int c = 0; c < 64; ++c) {
    v[((size_t)(b * 64 + c)) * S_LEN + s] = xv * w[c] + g * w[64 + c] + bias[c];
  }
}

// ---------------------------------------------------------------- DWT big: levels 8192->4101->2056->1033, 4 chunks/seq
__global__ __launch_bounds__(256) void dwt_big(
    const float* __restrict__ vin, float* __restrict__ highs, float* __restrict__ lo_f)
{
  __shared__ float sV[2184], sL1[1088], sL2[544];
  int seq = blockIdx.x >> 2, c = blockIdx.x & 3;
  const float* src = vin + (size_t)seq * S_LEN;
  float* hseq = highs + (size_t)seq * HTOT;

  int V0 = 2080 * c - 70;
  for (int i = threadIdx.x; i < 2178; i += 256)
    sV[i] = src[reflect_i(V0 + i, 8192)];
  __syncthreads();

  int base1 = 1040 * c - 30;
  for (int u = threadIdx.x; u < 1082; u += 256) {
    int m1 = base1 + u;
    float alo = 0.f, ahi = 0.f;
    #pragma unroll
    for (int k = 0; k < 12; ++k) {
      float x = sV[2 * m1 + k - 10 - V0];
      alo += x * rec_lo_c(k); ahi += x * rec_hi_c(k);
    }
    sL1[u] = alo;
    if (m1 >= 1040 * c && m1 < 1040 * c + 1040 && m1 >= 0 && m1 < 4101) hseq[m1] = ahi;
  }
  __syncthreads();

  int base2 = 520 * c - 10;
  for (int u = threadIdx.x; u < 534; u += 256) {
    int m2 = base2 + u;
    float alo = 0.f, ahi = 0.f;
    #pragma unroll
    for (int k = 0; k < 12; ++k) {
      int t = reflect_i(2 * m2 + k - 10, 4101);
      float x = sL1[t - base1];
      alo += x * rec_lo_c(k); ahi += x * rec_hi_c(k);
    }
    sL2[u] = alo;
    if (m2 >= 520 * c && m2 < 520 * c + 520 && m2 >= 0 && m2 < 2056) hseq[4101 + m2] = ahi;
  }
  __syncthreads();

  for (int u = threadIdx.x; u < 260; u += 256) {
    int m3 = 260 * c + u;
    if (m3 < 1033) {
      float alo = 0.f, ahi = 0.f;
      #pragma unroll
      for (int k = 0; k < 12; ++k) {
        int t = reflect_i(2 * m3 + k - 10, 2056);
        float x = sL2[t - base2];
        alo += x * rec_lo_c(k); ahi += x * rec_hi_c(k);
      }
      lo_f[(size_t)seq * 1033 + m3] = alo;
      hseq[6157 + m3] = ahi;
    }
  }
}

// ---------------------------------------------------------------- DWT small: 1033->522->266->138->74->42 per seq
__device__ __forceinline__ void dwt_lvl(const float* in, int n, float* out, int outn, float* hg)
{
  for (int m = threadIdx.x; m < outn; m += 256) {
    float alo = 0.f, ahi = 0.f;
    #pragma unroll
    for (int k = 0; k < 12; ++k) {
      float x = in[reflect_i(2 * m + k - 10, n)];
      alo += x * rec_lo_c(k); ahi += x * rec_hi_c(k);
    }
    out[m] = alo; hg[m] = ahi;
  }
  __syncthreads();
}

__global__ __launch_bounds__(256) void dwt_small(
    const float* __restrict__ lo_f, float* __restrict__ highs, float* __restrict__ yl)
{
  __shared__ float A[1040], Bb[528];
  int seq = blockIdx.x;
  const float* src = lo_f + (size_t)seq * 1033;
  float* hseq = highs + (size_t)seq * HTOT;
  for (int i = threadIdx.x; i < 1033; i += 256) A[i] = src[i];
  __syncthreads();
  dwt_lvl(A, 1033, Bb, 522, hseq + 7190);
  dwt_lvl(Bb, 522, A, 266, hseq + 7712);
  dwt_lvl(A, 266, Bb, 138, hseq + 7978);
  dwt_lvl(Bb, 138, A, 74, hseq + 8116);
  dwt_lvl(A, 74, Bb, 42, hseq + 8190);
  for (int m = threadIdx.x; m < MODES; m += 256) yl[seq * MODES + m] = Bb[m];
}

// ---------------------------------------------------------------- coarse-band channel mix
__global__ __launch_bounds__(256) void mix42(
    const float* __restrict__ in, int in_stride,
    const float* __restrict__ w, float* __restrict__ out)
{
  int idx = blockIdx.x * 256 + threadIdx.x;
  if (idx >= 32 * 64 * MODES) return;
  int xx = idx % MODES;
  int o  = (idx / MODES) % 64;
  int b  = idx / (MODES * 64);
  float acc = 0.f;
  for (int i = 0; i < 64; ++i)
    acc += in[((size_t)(b * 64 + i)) * in_stride + xx] * w[(i * 64 + o) * MODES + xx];
  out[(b * 64 + o) * MODES + xx] = acc;
}

// ---------------------------------------------------------------- IDWT small: 42->74->138->266->522->1033 per seq
// polyphase: m even uses taps k=2i+1, m odd k=2i; t0=(m-par)>>1, par = m&1 = tid&1 (stride 256, even bases)
__device__ __forceinline__ void idwt_lvl(const float* lo, const float* h, float* out, int outn)
{
  const int par = threadIdx.x & 1;
  for (int m = threadIdx.x; m < outn; m += 256) {
    int t0 = (m - par) >> 1;
    float acc = 0.f;
    #pragma unroll
    for (int i = 0; i < 6; ++i) {
      float cl = par ? dec_lo_c(2 * i) : dec_lo_c(2 * i + 1);
      float ch = par ? dec_hi_c(2 * i) : dec_hi_c(2 * i + 1);
      acc += lo[t0 + i] * cl + h[t0 + i] * ch;
    }
    out[m] = acc;
  }
}

__device__ __forceinline__ void stage_band(float* dst, const float* src, int len, int alloc)
{
  for (int i = threadIdx.x; i < alloc; i += 256) dst[i] = (i < len) ? src[i] : 0.f;
}

__global__ __launch_bounds__(256) void idwt_small(
    const float* __restrict__ yl_m, const float* __restrict__ yh_m,
    const float* __restrict__ highs, float* __restrict__ lo_i)
{
  __shared__ float bands[1132];   // yl@0(50) yh@50(50) h74@100(82) h138@182(146) h266@328(274) h522@602(530)
  __shared__ float wa[1040], wb[528];
  int seq = blockIdx.x;
  const float* hseq = highs + (size_t)seq * HTOT;
  stage_band(bands + 0,   yl_m + (size_t)seq * MODES, 42, 50);
  stage_band(bands + 50,  yh_m + (size_t)seq * MODES, 42, 50);
  stage_band(bands + 100, hseq + 8116, 74, 82);
  stage_band(bands + 182, hseq + 7978, 138, 146);
  stage_band(bands + 328, hseq + 7712, 266, 274);
  stage_band(bands + 602, hseq + 7190, 522, 530);
  __syncthreads();
  idwt_lvl(bands + 0, bands + 50, wa, 74);    __syncthreads();
  idwt_lvl(wa, bands + 100, wb, 138);         __syncthreads();
  idwt_lvl(wb, bands + 182, wa, 266);         __syncthreads();
  idwt_lvl(wa, bands + 328, wb, 522);         __syncthreads();
  // final small level: 522 -> 1034, keep 1033
  const int par = threadIdx.x & 1;
  for (int m = threadIdx.x; m < 1033; m += 256) {
    int t0 = (m - par) >> 1;
    float acc = 0.f;
    #pragma unroll
    for (int i = 0; i < 6; ++i) {
      float cl = par ? dec_lo_c(2 * i) : dec_lo_c(2 * i + 1);
      float ch = par ? dec_hi_c(2 * i) : dec_hi_c(2 * i + 1);
      acc += wb[t0 + i] * cl + bands[602 + t0 + i] * ch;
    }
    lo_i[(size_t)seq * 1033 + m] = acc;
  }
}

// ---------------------------------------------------------------- IDWT big: 1033->2056->4101->8192, 4 chunks/seq
__global__ __launch_bounds__(256) void idwt_big(
    const float* __restrict__ lo_i, const float* __restrict__ highs, float* __restrict__ x1)
{
  __shared__ float sL3[280], sH3[280], sL2[544], sH2[544], sL1[1040], sH1[1040];
  int seq = blockIdx.x >> 2, c = blockIdx.x & 3;
  const float* hseq = highs + (size_t)seq * HTOT;
  const float* l3   = lo_i + (size_t)seq * 1033;
  int b3 = 256 * c - 2, b2 = 512 * c - 2, b1 = 1024 * c - 2;
  const int par = threadIdx.x & 1;

  for (int i = threadIdx.x; i < 280; i += 256) {
    int g = b3 + i;
    bool ok = (g >= 0 && g < 1033);
    sL3[i] = ok ? l3[g] : 0.f;
    sH3[i] = ok ? hseq[6157 + g] : 0.f;
  }
  for (int i = threadIdx.x; i < 536; i += 256) {
    int g = b2 + i;
    sH2[i] = (g >= 0 && g < 2056) ? hseq[4101 + g] : 0.f;
  }
  for (int i = threadIdx.x; i < 1040; i += 256) {
    int g = b1 + i;
    sH1[i] = (g >= 0 && g < 4101) ? hseq[g] : 0.f;
  }
  __syncthreads();

  // s=5: len 1033 -> cover [b2, b2+536)
  for (int u = threadIdx.x; u < 536; u += 256) {
    int m = b2 + u;
    int t0 = ((m - par) >> 1) - b3;
    float acc = 0.f;
    #pragma unroll
    for (int i = 0; i < 6; ++i) {
      float cl = par ? dec_lo_c(2 * i) : dec_lo_c(2 * i + 1);
      float ch = par ? dec_hi_c(2 * i) : dec_hi_c(2 * i + 1);
      acc += sL3[t0 + i] * cl + sH3[t0 + i] * ch;
    }
    sL2[u] = (m >= 0 && m < 2056) ? acc : 0.f;
  }
  __syncthreads();

  // s=6: len 2056 -> cover [b1, b1+1040), truncate >=4101 to 0
  for (int u = threadIdx.x; u < 1040; u += 256) {
    int m = b1 + u;
    int t0 = ((m - par) >> 1) - b2;
    float acc = 0.f;
    #pragma unroll
    for (int i = 0; i < 6; ++i) {
      float cl = par ? dec_lo_c(2 * i) : dec_lo_c(2 * i + 1);
      float ch = par ? dec_hi_c(2 * i) : dec_hi_c(2 * i + 1);
      acc += sL2[t0 + i] * cl + sH2[t0 + i] * ch;
    }
    sL1[u] = (m >= 0 && m < 4101) ? acc : 0.f;
  }
  __syncthreads();

  // s=7: len 4101 -> out [2048c, 2048c+2048)
  for (int u = threadIdx.x; u < 2048; u += 256) {
    int m = 2048 * c + u;
    int t0 = ((m - par) >> 1) - b1;
    float acc = 0.f;
    #pragma unroll
    for (int i = 0; i < 6; ++i) {
      float cl = par ? dec_lo_c(2 * i) : dec_lo_c(2 * i + 1);
      float ch = par ? dec_hi_c(2 * i) : dec_hi_c(2 * i + 1);
      acc += sL1[t0 + i] * cl + sH1[t0 + i] * ch;
    }
    x1[(size_t)seq * S_LEN + m] = acc;
  }
}

// ---------------------------------------------------------------- per-layer pointwise: v = gelu?(x1 + v@cw + cb)
__global__ __launch_bounds__(256) void layer_pw(
    const float* __restrict__ x1, float* __restrict__ v,
    const float* __restrict__ cw, const float* __restrict__ cb, int do_gelu)
{
  __shared__ float vt[64][65];
  int b  = blockIdx.x >> 7;
  int s0 = (blockIdx.x & 127) << 6;
  int t  = threadIdx.x;
  int sl = t & 63;
  int wv = __builtin_amdgcn_readfirstlane(t >> 6);

  for (int r = 0; r < 16; ++r) {
    int idx = t + 256 * r;
    int i = idx >> 6, s = idx & 63;
    vt[i][s] = v[((size_t)(b * 64 + i)) * S_LEN + s0 + s];
  }
  __syncthreads();

  float vr[64];
  #pragma unroll
  for (int i = 0; i < 64; ++i) vr[i] = vt[i][sl];

  for (int r = 0; r < 16; ++r) {
    int o = wv * 16 + r;
    float acc = cb[o];
    #pragma unroll
    for (int i = 0; i < 64; ++i) acc += vr[i] * cw[i * 64 + o];
    float y = x1[((size_t)(b * 64 + o)) * S_LEN + s0 + sl] + acc;
    if (do_gelu) y = gelu_f(y);
    v[((size_t)(b * 64 + o)) * S_LEN + s0 + sl] = y;
  }
}

// ---------------------------------------------------------------- head
__global__ __launch_bounds__(256) void head_kernel(
    const float* __restrict__ v, const float* __restrict__ fc1w,
    const float* __restrict__ fc1b, const float* __restrict__ fc2w,
    const float* __restrict__ fc2b, float* __restrict__ out)
{
  int p = blockIdx.x * 256 + threadIdx.x;
  int b = p >> 13, s = p & 8191;
  float vr[64];
  #pragma unroll
  for (int c = 0; c < 64; ++c) vr[c] = v[((size_t)(b * 64 + c)) * S_LEN + s];
  float res = fc2b[0];
  for (int j = 0; j < 128; ++j) {
    float d = fc1b[j];
    #pragma unroll
    for (int c = 0; c < 64; ++c) d += vr[c] * fc1w[c * 128 + j];
    res += fc2w[j] * gelu_f(d);
  }
  out[p] = res;
}

// ----------------------------------------------------------------
extern "C" void kernel_launch(void* const* d_in, const int* in_sizes, int n_in,
                              void* d_out, int out_size, void* d_ws, size_t ws_size,
                              hipStream_t stream) {
  const float* x    = (const float*)d_in[0];
  const float* fc0w = (const float*)d_in[1];
  const float* fc0b = (const float*)d_in[2];
  const float* w1   = (const float*)d_in[3];
  const float* w2   = (const float*)d_in[4];
  const float* cw   = (const float*)d_in[5];
  const float* cb   = (const float*)d_in[6];
  const float* fc1w = (const float*)d_in[7];
  const float* fc1b = (const float*)d_in[8];
  const float* fc2w = (const float*)d_in[9];
  const float* fc2b = (const float*)d_in[10];
  float* out = (float*)d_out;

  float* ws     = (float*)d_ws;
  float* v      = ws;
  float* x1     = v      + (size_t)BC * S_LEN;
  float* highs  = x1     + (size_t)BC * S_LEN;
  float* yl_raw = highs  + (size_t)BC * HTOT;
  float* yl_m   = yl_raw + (size_t)BC * MODES;
  float* yh_m   = yl_m   + (size_t)BC * MODES;
  float* lo_f   = yh_m   + (size_t)BC * MODES;
  float* lo_i   = lo_f   + (size_t)BC * 1033;
  size_t needed = (size_t)((lo_i + (size_t)BC * 1033) - ws) * sizeof(float);
  if (ws_size < needed) return;

  fc0_kernel<<<1024, 256, 0, stream>>>(x, fc0w, fc0b, v);

  for (int i = 0; i < 4; ++i) {
    dwt_big<<<BC * 4, 256, 0, stream>>>(v, highs, lo_f);
    dwt_small<<<BC, 256, 0, stream>>>(lo_f, highs, yl_raw);
    mix42<<<336, 256, 0, stream>>>(yl_raw, MODES, w1 + (size_t)i * 64 * 64 * MODES, yl_m);
    mix42<<<336, 256, 0, stream>>>(highs + 8190, HTOT, w2 + (size_t)i * 64 * 64 * MODES, yh_m);
    idwt_small<<<BC, 256, 0, stream>>>(yl_m, yh_m, highs, lo_i);
    idwt_big<<<BC * 4, 256, 0, stream>>>(lo_i, highs, x1);
    layer_pw<<<4096, 256, 0, stream>>>(x1, v, cw + i * 4096, cb + i * 64, (i < 3) ? 1 : 0);
  }

  head_kernel<<<1024, 256, 0, stream>>>(v, fc1w, fc1b, fc2w, fc2b, out);
}

// Round 5
// 680.187 us; speedup vs baseline: 2.7132x; 1.2458x over previous
//
#include <hip/hip_runtime.h>
#include <cmath>

#define BC 2048          // B*W sequences
#define S_LEN 8192
#define MODES 42
#define HTOT 8232        // packed high-band pyramid: offs {0,4101,6157,7190,7712,7978,8116,8190}

static constexpr float C_LO[12] = {
  0.11154074335008017f, 0.4946238903983854f, 0.7511339080215775f,
  0.3152503517092432f, -0.22626469396516913f, -0.12976686756709563f,
  0.09750160558707936f, 0.02752286553001629f, -0.031582039318031156f,
  0.0005538422009938016f, 0.004777257511010651f, -0.00107730108499558f };

__device__ __forceinline__ float rec_lo_c(int k){ return C_LO[k]; }
__device__ __forceinline__ float rec_hi_c(int k){ float v = C_LO[11-k]; return (k&1)? -v : v; }
__device__ __forceinline__ float dec_lo_c(int k){ return C_LO[11-k]; }
__device__ __forceinline__ float dec_hi_c(int k){ float v = C_LO[k];    return (k&1)?  v : -v; }

__device__ __forceinline__ float gelu_f(float x){
  return 0.5f * x * (1.0f + erff(x * 0.70710678118654752440f));
}

__device__ __forceinline__ int reflect_i(int t, int n){
  t = (t < 0) ? (-1 - t) : t;
  t = (t >= n) ? (2 * n - 1 - t) : t;
  return t;
}

// bf16 hi/lo split helpers
__device__ __forceinline__ unsigned short bf16_rn(float x){
  unsigned int b = __float_as_uint(x);
  b += 0x7FFF + ((b >> 16) & 1);
  return (unsigned short)(b >> 16);
}
__device__ __forceinline__ float bf16_to_f(unsigned short h){
  return __uint_as_float(((unsigned int)h) << 16);
}

typedef short  v8s __attribute__((ext_vector_type(8)));
typedef float  v4f __attribute__((ext_vector_type(4)));

// ---------------------------------------------------------------- fc0
__global__ __launch_bounds__(256) void fc0_kernel(
    const float* __restrict__ x, const float* __restrict__ w,
    const float* __restrict__ bias, float* __restrict__ v)
{
  int p = blockIdx.x * 256 + threadIdx.x;   // p = b*8192 + s
  int b = p >> 13, s = p & 8191;
  float xv = x[p];
  float g  = (float)s * (1.0f / 8191.0f);
  for (int c = 0; c < 64; ++c) {
    v[((size_t)(b * 64 + c)) * S_LEN + s] = xv * w[c] + g * w[64 + c] + bias[c];
  }
}

// ---------------------------------------------------------------- DWT big: levels 8192->4101->2056->1033, 4 chunks/seq
__global__ __launch_bounds__(256) void dwt_big(
    const float* __restrict__ vin, float* __restrict__ highs, float* __restrict__ lo_f)
{
  __shared__ float sV[2184], sL1[1088], sL2[544];
  int seq = blockIdx.x >> 2, c = blockIdx.x & 3;
  const float* src = vin + (size_t)seq * S_LEN;
  float* hseq = highs + (size_t)seq * HTOT;

  int V0 = 2080 * c - 70;
  for (int i = threadIdx.x; i < 2178; i += 256)
    sV[i] = src[reflect_i(V0 + i, 8192)];
  __syncthreads();

  int base1 = 1040 * c - 30;
  for (int u = threadIdx.x; u < 1082; u += 256) {
    int m1 = base1 + u;
    float alo = 0.f, ahi = 0.f;
    #pragma unroll
    for (int k = 0; k < 12; ++k) {
      float x = sV[2 * m1 + k - 10 - V0];
      alo += x * rec_lo_c(k); ahi += x * rec_hi_c(k);
    }
    sL1[u] = alo;
    if (m1 >= 1040 * c && m1 < 1040 * c + 1040 && m1 >= 0 && m1 < 4101) hseq[m1] = ahi;
  }
  __syncthreads();

  int base2 = 520 * c - 10;
  for (int u = threadIdx.x; u < 534; u += 256) {
    int m2 = base2 + u;
    float alo = 0.f, ahi = 0.f;
    #pragma unroll
    for (int k = 0; k < 12; ++k) {
      int t = reflect_i(2 * m2 + k - 10, 4101);
      float x = sL1[t - base1];
      alo += x * rec_lo_c(k); ahi += x * rec_hi_c(k);
    }
    sL2[u] = alo;
    if (m2 >= 520 * c && m2 < 520 * c + 520 && m2 >= 0 && m2 < 2056) hseq[4101 + m2] = ahi;
  }
  __syncthreads();

  for (int u = threadIdx.x; u < 260; u += 256) {
    int m3 = 260 * c + u;
    if (m3 < 1033) {
      float alo = 0.f, ahi = 0.f;
      #pragma unroll
      for (int k = 0; k < 12; ++k) {
        int t = reflect_i(2 * m3 + k - 10, 2056);
        float x = sL2[t - base2];
        alo += x * rec_lo_c(k); ahi += x * rec_hi_c(k);
      }
      lo_f[(size_t)seq * 1033 + m3] = alo;
      hseq[6157 + m3] = ahi;
    }
  }
}

// ---------------------------------------------------------------- DWT small: 1033->522->266->138->74->42 per seq
__device__ __forceinline__ void dwt_lvl(const float* in, int n, float* out, int outn, float* hg)
{
  for (int m = threadIdx.x; m < outn; m += 256) {
    float alo = 0.f, ahi = 0.f;
    #pragma unroll
    for (int k = 0; k < 12; ++k) {
      float x = in[reflect_i(2 * m + k - 10, n)];
      alo += x * rec_lo_c(k); ahi += x * rec_hi_c(k);
    }
    out[m] = alo; hg[m] = ahi;
  }
  __syncthreads();
}

__global__ __launch_bounds__(256) void dwt_small(
    const float* __restrict__ lo_f, float* __restrict__ highs, float* __restrict__ yl)
{
  __shared__ float A[1040], Bb[528];
  int seq = blockIdx.x;
  const float* src = lo_f + (size_t)seq * 1033;
  float* hseq = highs + (size_t)seq * HTOT;
  for (int i = threadIdx.x; i < 1033; i += 256) A[i] = src[i];
  __syncthreads();
  dwt_lvl(A, 1033, Bb, 522, hseq + 7190);
  dwt_lvl(Bb, 522, A, 266, hseq + 7712);
  dwt_lvl(A, 266, Bb, 138, hseq + 7978);
  dwt_lvl(Bb, 138, A, 74, hseq + 8116);
  dwt_lvl(A, 74, Bb, 42, hseq + 8190);
  for (int m = threadIdx.x; m < MODES; m += 256) yl[seq * MODES + m] = Bb[m];
}

// ---------------------------------------------------------------- coarse-band channel mix
__global__ __launch_bounds__(256) void mix42(
    const float* __restrict__ in, int in_stride,
    const float* __restrict__ w, float* __restrict__ out)
{
  int idx = blockIdx.x * 256 + threadIdx.x;
  if (idx >= 32 * 64 * MODES) return;
  int xx = idx % MODES;
  int o  = (idx / MODES) % 64;
  int b  = idx / (MODES * 64);
  float acc = 0.f;
  for (int i = 0; i < 64; ++i)
    acc += in[((size_t)(b * 64 + i)) * in_stride + xx] * w[(i * 64 + o) * MODES + xx];
  out[(b * 64 + o) * MODES + xx] = acc;
}

// ---------------------------------------------------------------- IDWT small: 42->...->1033 per seq (polyphase)
__device__ __forceinline__ void idwt_lvl(const float* lo, const float* h, float* out, int outn)
{
  const int par = threadIdx.x & 1;
  for (int m = threadIdx.x; m < outn; m += 256) {
    int t0 = (m - par) >> 1;
    float acc = 0.f;
    #pragma unroll
    for (int i = 0; i < 6; ++i) {
      float cl = par ? dec_lo_c(2 * i) : dec_lo_c(2 * i + 1);
      float ch = par ? dec_hi_c(2 * i) : dec_hi_c(2 * i + 1);
      acc += lo[t0 + i] * cl + h[t0 + i] * ch;
    }
    out[m] = acc;
  }
}

__device__ __forceinline__ void stage_band(float* dst, const float* src, int len, int alloc)
{
  for (int i = threadIdx.x; i < alloc; i += 256) dst[i] = (i < len) ? src[i] : 0.f;
}

__global__ __launch_bounds__(256) void idwt_small(
    const float* __restrict__ yl_m, const float* __restrict__ yh_m,
    const float* __restrict__ highs, float* __restrict__ lo_i)
{
  __shared__ float bands[1132];
  __shared__ float wa[1040], wb[528];
  int seq = blockIdx.x;
  const float* hseq = highs + (size_t)seq * HTOT;
  stage_band(bands + 0,   yl_m + (size_t)seq * MODES, 42, 50);
  stage_band(bands + 50,  yh_m + (size_t)seq * MODES, 42, 50);
  stage_band(bands + 100, hseq + 8116, 74, 82);
  stage_band(bands + 182, hseq + 7978, 138, 146);
  stage_band(bands + 328, hseq + 7712, 266, 274);
  stage_band(bands + 602, hseq + 7190, 522, 530);
  __syncthreads();
  idwt_lvl(bands + 0, bands + 50, wa, 74);    __syncthreads();
  idwt_lvl(wa, bands + 100, wb, 138);         __syncthreads();
  idwt_lvl(wb, bands + 182, wa, 266);         __syncthreads();
  idwt_lvl(wa, bands + 328, wb, 522);         __syncthreads();
  const int par = threadIdx.x & 1;
  for (int m = threadIdx.x; m < 1033; m += 256) {
    int t0 = (m - par) >> 1;
    float acc = 0.f;
    #pragma unroll
    for (int i = 0; i < 6; ++i) {
      float cl = par ? dec_lo_c(2 * i) : dec_lo_c(2 * i + 1);
      float ch = par ? dec_hi_c(2 * i) : dec_hi_c(2 * i + 1);
      acc += wb[t0 + i] * cl + bands[602 + t0 + i] * ch;
    }
    lo_i[(size_t)seq * 1033 + m] = acc;
  }
}

// ---------------------------------------------------------------- IDWT big: 1033->2056->4101->8192, 4 chunks/seq
__global__ __launch_bounds__(256) void idwt_big(
    const float* __restrict__ lo_i, const float* __restrict__ highs, float* __restrict__ x1)
{
  __shared__ float sL3[280], sH3[280], sL2[544], sH2[544], sL1[1040], sH1[1040];
  int seq = blockIdx.x >> 2, c = blockIdx.x & 3;
  const float* hseq = highs + (size_t)seq * HTOT;
  const float* l3   = lo_i + (size_t)seq * 1033;
  int b3 = 256 * c - 2, b2 = 512 * c - 2, b1 = 1024 * c - 2;
  const int par = threadIdx.x & 1;

  for (int i = threadIdx.x; i < 280; i += 256) {
    int g = b3 + i;
    bool ok = (g >= 0 && g < 1033);
    sL3[i] = ok ? l3[g] : 0.f;
    sH3[i] = ok ? hseq[6157 + g] : 0.f;
  }
  for (int i = threadIdx.x; i < 536; i += 256) {
    int g = b2 + i;
    sH2[i] = (g >= 0 && g < 2056) ? hseq[4101 + g] : 0.f;
  }
  for (int i = threadIdx.x; i < 1040; i += 256) {
    int g = b1 + i;
    sH1[i] = (g >= 0 && g < 4101) ? hseq[g] : 0.f;
  }
  __syncthreads();

  for (int u = threadIdx.x; u < 536; u += 256) {
    int m = b2 + u;
    int t0 = ((m - par) >> 1) - b3;
    float acc = 0.f;
    #pragma unroll
    for (int i = 0; i < 6; ++i) {
      float cl = par ? dec_lo_c(2 * i) : dec_lo_c(2 * i + 1);
      float ch = par ? dec_hi_c(2 * i) : dec_hi_c(2 * i + 1);
      acc += sL3[t0 + i] * cl + sH3[t0 + i] * ch;
    }
    sL2[u] = (m >= 0 && m < 2056) ? acc : 0.f;
  }
  __syncthreads();

  for (int u = threadIdx.x; u < 1040; u += 256) {
    int m = b1 + u;
    int t0 = ((m - par) >> 1) - b2;
    float acc = 0.f;
    #pragma unroll
    for (int i = 0; i < 6; ++i) {
      float cl = par ? dec_lo_c(2 * i) : dec_lo_c(2 * i + 1);
      float ch = par ? dec_hi_c(2 * i) : dec_hi_c(2 * i + 1);
      acc += sL2[t0 + i] * cl + sH2[t0 + i] * ch;
    }
    sL1[u] = (m >= 0 && m < 4101) ? acc : 0.f;
  }
  __syncthreads();

  for (int u = threadIdx.x; u < 2048; u += 256) {
    int m = 2048 * c + u;
    int t0 = ((m - par) >> 1) - b1;
    float acc = 0.f;
    #pragma unroll
    for (int i = 0; i < 6; ++i) {
      float cl = par ? dec_lo_c(2 * i) : dec_lo_c(2 * i + 1);
      float ch = par ? dec_hi_c(2 * i) : dec_hi_c(2 * i + 1);
      acc += sL1[t0 + i] * cl + sH1[t0 + i] * ch;
    }
    x1[(size_t)seq * S_LEN + m] = acc;
  }
}

// ---------------------------------------------------------------- layer pointwise via MFMA (split bf16):
// v[o][pos] = gelu?( x1[o][pos] + sum_i v[i][pos]*cw[i][o] + cb[o] )
__global__ __launch_bounds__(256) void pw_mfma(
    const float* __restrict__ x1, float* v,
    const float* __restrict__ cw, const float* __restrict__ cb, int do_gelu)
{
  __shared__ unsigned short aH[64][64], aL[64][64];   // A-tile [pos][ch] swizzled
  __shared__ unsigned short wH[64][64], wL[64][64];   // W^T   [o][ch]   swizzled
  __shared__ float cbl[64];
  int b  = blockIdx.x >> 7;
  int s0 = (blockIdx.x & 127) << 6;
  int t  = threadIdx.x;

  for (int r = 0; r < 16; ++r) {
    int idx = t + 256 * r;             // cw[c*64+o]
    int c = idx >> 6, o = idx & 63;
    float wv = cw[idx];
    unsigned short h = bf16_rn(wv);
    float lo = wv - bf16_to_f(h);
    int cs = c ^ ((o & 7) << 3);
    wH[o][cs] = h; wL[o][cs] = bf16_rn(lo);
  }
  if (t < 64) cbl[t] = cb[t];
  for (int r = 0; r < 16; ++r) {
    int idx = t + 256 * r;
    int ch = idx >> 6, p = idx & 63;
    float x = v[((size_t)(b * 64 + ch)) * S_LEN + s0 + p];
    unsigned short h = bf16_rn(x);
    float lo = x - bf16_to_f(h);
    int cs = ch ^ ((p & 7) << 3);
    aH[p][cs] = h; aL[p][cs] = bf16_rn(lo);
  }
  __syncthreads();

  int l = t & 63, wv_ = t >> 6;        // 4 waves, each owns 16 pos
  int pi = l & 15, kg = l >> 4;        // frag: idx=pi, k-chunk=kg
  int pos = wv_ * 16 + pi;
  int swz = (pi & 7) << 3;             // pos&7 == pi&7 ; o&7 == pi&7

  v4f acc[4];
  #pragma unroll
  for (int i = 0; i < 4; ++i) acc[i] = v4f{0.f, 0.f, 0.f, 0.f};

  #pragma unroll
  for (int kt = 0; kt < 2; ++kt) {
    int ka = (kg * 8 + kt * 32) ^ swz;
    v8s ah = *(const v8s*)&aH[pos][ka];
    v8s al = *(const v8s*)&aL[pos][ka];
    #pragma unroll
    for (int ct = 0; ct < 4; ++ct) {
      int o = ct * 16 + pi;
      v8s bh = *(const v8s*)&wH[o][ka];
      v8s bl = *(const v8s*)&wL[o][ka];
      acc[ct] = __builtin_amdgcn_mfma_f32_16x16x32_bf16(ah, bh, acc[ct], 0, 0, 0);
      acc[ct] = __builtin_amdgcn_mfma_f32_16x16x32_bf16(ah, bl, acc[ct], 0, 0, 0);
      acc[ct] = __builtin_amdgcn_mfma_f32_16x16x32_bf16(al, bh, acc[ct], 0, 0, 0);
    }
  }

  // D: col(o)=lane&15 per ct, rows = kg*4 + r
  #pragma unroll
  for (int ct = 0; ct < 4; ++ct) {
    int o = ct * 16 + pi;
    size_t base = ((size_t)(b * 64 + o)) * S_LEN + s0 + wv_ * 16 + kg * 4;
    float4 x4 = *(const float4*)&x1[base];
    float cbv = cbl[o];
    float y0 = acc[ct][0] + x4.x + cbv;
    float y1 = acc[ct][1] + x4.y + cbv;
    float y2 = acc[ct][2] + x4.z + cbv;
    float y3 = acc[ct][3] + x4.w + cbv;
    if (do_gelu) { y0 = gelu_f(y0); y1 = gelu_f(y1); y2 = gelu_f(y2); y3 = gelu_f(y3); }
    float4 y4 = make_float4(y0, y1, y2, y3);
    *(float4*)&v[base] = y4;
  }
}

// ---------------------------------------------------------------- head via MFMA: out = gelu(v^T@fc1+b1)@fc2+b2
__global__ __launch_bounds__(256) void head_mfma(
    const float* __restrict__ v, const float* __restrict__ fc1w,
    const float* __restrict__ fc1b, const float* __restrict__ fc2w,
    const float* __restrict__ fc2b, float* __restrict__ out)
{
  __shared__ unsigned short aH[64][64], aL[64][64];     // A [pos][ch]
  __shared__ unsigned short wH[128][64], wL[128][64];   // fc1^T [j][ch]
  __shared__ float f1b[128], f2w[128];
  int b  = blockIdx.x >> 7;
  int s0 = (blockIdx.x & 127) << 6;
  int t  = threadIdx.x;

  for (int r = 0; r < 32; ++r) {
    int idx = t + 256 * r;             // fc1w[c*128+j]
    int c = idx >> 7, j = idx & 127;
    float wv = fc1w[idx];
    unsigned short h = bf16_rn(wv);
    float lo = wv - bf16_to_f(h);
    int cs = c ^ ((j & 7) << 3);
    wH[j][cs] = h; wL[j][cs] = bf16_rn(lo);
  }
  if (t < 128) { f1b[t] = fc1b[t]; f2w[t] = fc2w[t]; }
  for (int r = 0; r < 16; ++r) {
    int idx = t + 256 * r;
    int ch = idx >> 6, p = idx & 63;
    float x = v[((size_t)(b * 64 + ch)) * S_LEN + s0 + p];
    unsigned short h = bf16_rn(x);
    float lo = x - bf16_to_f(h);
    int cs = ch ^ ((p & 7) << 3);
    aH[p][cs] = h; aL[p][cs] = bf16_rn(lo);
  }
  __syncthreads();

  int l = t & 63, wv_ = t >> 6;
  int pi = l & 15, kg = l >> 4;
  int pos = wv_ * 16 + pi;
  int swz = (pi & 7) << 3;

  v4f acc[8];
  #pragma unroll
  for (int i = 0; i < 8; ++i) acc[i] = v4f{0.f, 0.f, 0.f, 0.f};

  #pragma unroll
  for (int kt = 0; kt < 2; ++kt) {
    int ka = (kg * 8 + kt * 32) ^ swz;
    v8s ah = *(const v8s*)&aH[pos][ka];
    v8s al = *(const v8s*)&aL[pos][ka];
    #pragma unroll
    for (int ct = 0; ct < 8; ++ct) {
      int j = ct * 16 + pi;
      v8s bh = *(const v8s*)&wH[j][ka];
      v8s bl = *(const v8s*)&wL[j][ka];
      acc[ct] = __builtin_amdgcn_mfma_f32_16x16x32_bf16(ah, bh, acc[ct], 0, 0, 0);
      acc[ct] = __builtin_amdgcn_mfma_f32_16x16x32_bf16(ah, bl, acc[ct], 0, 0, 0);
      acc[ct] = __builtin_amdgcn_mfma_f32_16x16x32_bf16(al, bh, acc[ct], 0, 0, 0);
    }
  }

  float part[4] = {0.f, 0.f, 0.f, 0.f};
  #pragma unroll
  for (int ct = 0; ct < 8; ++ct) {
    int j = ct * 16 + pi;
    float bias = f1b[j], f2 = f2w[j];
    #pragma unroll
    for (int r = 0; r < 4; ++r) {
      float d = acc[ct][r] + bias;
      part[r] += f2 * gelu_f(d);
    }
  }
  #pragma unroll
  for (int r = 0; r < 4; ++r) {
    part[r] += __shfl_xor(part[r], 1, 16);
    part[r] += __shfl_xor(part[r], 2, 16);
    part[r] += __shfl_xor(part[r], 4, 16);
    part[r] += __shfl_xor(part[r], 8, 16);
  }
  if (pi == 0) {
    float b2 = fc2b[0];
    float4 o4 = make_float4(part[0] + b2, part[1] + b2, part[2] + b2, part[3] + b2);
    *(float4*)&out[(size_t)b * S_LEN + s0 + wv_ * 16 + kg * 4] = o4;
  }
}

// ----------------------------------------------------------------
extern "C" void kernel_launch(void* const* d_in, const int* in_sizes, int n_in,
                              void* d_out, int out_size, void* d_ws, size_t ws_size,
                              hipStream_t stream) {
  const float* x    = (const float*)d_in[0];
  const float* fc0w = (const float*)d_in[1];
  const float* fc0b = (const float*)d_in[2];
  const float* w1   = (const float*)d_in[3];
  const float* w2   = (const float*)d_in[4];
  const float* cw   = (const float*)d_in[5];
  const float* cb   = (const float*)d_in[6];
  const float* fc1w = (const float*)d_in[7];
  const float* fc1b = (const float*)d_in[8];
  const float* fc2w = (const float*)d_in[9];
  const float* fc2b = (const float*)d_in[10];
  float* out = (float*)d_out;

  float* ws     = (float*)d_ws;
  float* v      = ws;
  float* x1     = v      + (size_t)BC * S_LEN;
  float* highs  = x1     + (size_t)BC * S_LEN;
  float* yl_raw = highs  + (size_t)BC * HTOT;
  float* yl_m   = yl_raw + (size_t)BC * MODES;
  float* yh_m   = yl_m   + (size_t)BC * MODES;
  float* lo_f   = yh_m   + (size_t)BC * MODES;
  float* lo_i   = lo_f   + (size_t)BC * 1033;
  size_t needed = (size_t)((lo_i + (size_t)BC * 1033) - ws) * sizeof(float);
  if (ws_size < needed) return;

  fc0_kernel<<<1024, 256, 0, stream>>>(x, fc0w, fc0b, v);

  for (int i = 0; i < 4; ++i) {
    dwt_big<<<BC * 4, 256, 0, stream>>>(v, highs, lo_f);
    dwt_small<<<BC, 256, 0, stream>>>(lo_f, highs, yl_raw);
    mix42<<<336, 256, 0, stream>>>(yl_raw, MODES, w1 + (size_t)i * 64 * 64 * MODES, yl_m);
    mix42<<<336, 256, 0, stream>>>(highs + 8190, HTOT, w2 + (size_t)i * 64 * 64 * MODES, yh_m);
    idwt_small<<<BC, 256, 0, stream>>>(yl_m, yh_m, highs, lo_i);
    idwt_big<<<BC * 4, 256, 0, stream>>>(lo_i, highs, x1);
    pw_mfma<<<4096, 256, 0, stream>>>(x1, v, cw + i * 4096, cb + i * 64, (i < 3) ? 1 : 0);
  }

  head_mfma<<<4096, 256, 0, stream>>>(v, fc1w, fc1b, fc2w, fc2b, out);
}

// Round 6
// 641.279 us; speedup vs baseline: 2.8778x; 1.0607x over previous
//
#include <hip/hip_runtime.h>
#include <cmath>

#define BC 2048          // B*W sequences
#define S_LEN 8192
#define MODES 42
#define HTOT 8232        // packed high-band pyramid: offs {0,4101,6157,7190,7712,7978,8116,8190}

static constexpr float C_LO[12] = {
  0.11154074335008017f, 0.4946238903983854f, 0.7511339080215775f,
  0.3152503517092432f, -0.22626469396516913f, -0.12976686756709563f,
  0.09750160558707936f, 0.02752286553001629f, -0.031582039318031156f,
  0.0005538422009938016f, 0.004777257511010651f, -0.00107730108499558f };

__device__ __forceinline__ float rec_lo_c(int k){ return C_LO[k]; }
__device__ __forceinline__ float rec_hi_c(int k){ float v = C_LO[11-k]; return (k&1)? -v : v; }
__device__ __forceinline__ float dec_lo_c(int k){ return C_LO[11-k]; }
__device__ __forceinline__ float dec_hi_c(int k){ float v = C_LO[k];    return (k&1)?  v : -v; }

// branchless erf (Abramowitz-Stegun 7.1.26, |err|<=1.5e-7)
__device__ __forceinline__ float erf_fast(float x){
  float ax = fabsf(x);
  float t  = __fdividef(1.0f, 1.0f + 0.3275911f * ax);
  float p  = ((((1.061405429f * t - 1.453152027f) * t) + 1.421413741f) * t - 0.284496736f) * t + 0.254829592f;
  float y  = 1.0f - p * t * __expf(-ax * ax);
  return copysignf(y, x);
}
__device__ __forceinline__ float gelu_f(float x){
  return 0.5f * x * (1.0f + erf_fast(x * 0.70710678118654752440f));
}

__device__ __forceinline__ int reflect_i(int t, int n){
  t = (t < 0) ? (-1 - t) : t;
  t = (t >= n) ? (2 * n - 1 - t) : t;
  return t;
}

// bf16 hi/lo split helpers
__device__ __forceinline__ unsigned short bf16_rn(float x){
  unsigned int b = __float_as_uint(x);
  b += 0x7FFF + ((b >> 16) & 1);
  return (unsigned short)(b >> 16);
}
__device__ __forceinline__ float bf16_to_f(unsigned short h){
  return __uint_as_float(((unsigned int)h) << 16);
}

typedef short  v8s __attribute__((ext_vector_type(8)));
typedef float  v4f __attribute__((ext_vector_type(4)));
typedef unsigned short u16;

// ---------------------------------------------------------------- prep: split weights to hi/lo bf16 in swizzled LDS layout
__global__ __launch_bounds__(256) void prep_split(
    const float* __restrict__ fc1w, const float* __restrict__ cw,
    u16* __restrict__ whH, u16* __restrict__ whL,
    u16* __restrict__ wcH, u16* __restrict__ wcL)
{
  int i = blockIdx.x * 256 + threadIdx.x;
  if (i < 8192) {                       // fc1w[c*128+j] -> [j][c^((j&7)<<3)]
    int c = i >> 7, j = i & 127;
    float wv = fc1w[i];
    u16 h = bf16_rn(wv);
    float lo = wv - bf16_to_f(h);
    int cs = c ^ ((j & 7) << 3);
    whH[j * 64 + cs] = h; whL[j * 64 + cs] = bf16_rn(lo);
  }
  int k = i - 8192;
  if (k >= 0 && k < 16384) {            // cw[l][c][o] -> [l][o][c^((o&7)<<3)]
    int l = k >> 12, r = k & 4095;
    int c = r >> 6, o = r & 63;
    float wv = cw[k];
    u16 h = bf16_rn(wv);
    float lo = wv - bf16_to_f(h);
    int cs = c ^ ((o & 7) << 3);
    wcH[l * 4096 + o * 64 + cs] = h; wcL[l * 4096 + o * 64 + cs] = bf16_rn(lo);
  }
}

// ---------------------------------------------------------------- fc0
__global__ __launch_bounds__(256) void fc0_kernel(
    const float* __restrict__ x, const float* __restrict__ w,
    const float* __restrict__ bias, float* __restrict__ v)
{
  int p = blockIdx.x * 256 + threadIdx.x;   // p = b*8192 + s
  int b = p >> 13, s = p & 8191;
  float xv = x[p];
  float g  = (float)s * (1.0f / 8191.0f);
  for (int c = 0; c < 64; ++c) {
    v[((size_t)(b * 64 + c)) * S_LEN + s] = xv * w[c] + g * w[64 + c] + bias[c];
  }
}

// ---------------------------------------------------------------- DWT big: levels 8192->4101->2056->1033, 4 chunks/seq
__global__ __launch_bounds__(256) void dwt_big(
    const float* __restrict__ vin, float* __restrict__ highs, float* __restrict__ lo_f)
{
  __shared__ float sV[2184], sL1[1088], sL2[544];
  int seq = blockIdx.x >> 2, c = blockIdx.x & 3;
  const float* src = vin + (size_t)seq * S_LEN;
  float* hseq = highs + (size_t)seq * HTOT;

  int V0 = 2080 * c - 70;
  for (int i = threadIdx.x; i < 2178; i += 256)
    sV[i] = src[reflect_i(V0 + i, 8192)];
  __syncthreads();

  int base1 = 1040 * c - 30;
  for (int u = threadIdx.x; u < 1082; u += 256) {
    int m1 = base1 + u;
    float alo = 0.f, ahi = 0.f;
    #pragma unroll
    for (int k = 0; k < 12; ++k) {
      float x = sV[2 * m1 + k - 10 - V0];
      alo += x * rec_lo_c(k); ahi += x * rec_hi_c(k);
    }
    sL1[u] = alo;
    if (m1 >= 1040 * c && m1 < 1040 * c + 1040 && m1 >= 0 && m1 < 4101) hseq[m1] = ahi;
  }
  __syncthreads();

  int base2 = 520 * c - 10;
  for (int u = threadIdx.x; u < 534; u += 256) {
    int m2 = base2 + u;
    float alo = 0.f, ahi = 0.f;
    #pragma unroll
    for (int k = 0; k < 12; ++k) {
      int t = reflect_i(2 * m2 + k - 10, 4101);
      float x = sL1[t - base1];
      alo += x * rec_lo_c(k); ahi += x * rec_hi_c(k);
    }
    sL2[u] = alo;
    if (m2 >= 520 * c && m2 < 520 * c + 520 && m2 >= 0 && m2 < 2056) hseq[4101 + m2] = ahi;
  }
  __syncthreads();

  for (int u = threadIdx.x; u < 260; u += 256) {
    int m3 = 260 * c + u;
    if (m3 < 1033) {
      float alo = 0.f, ahi = 0.f;
      #pragma unroll
      for (int k = 0; k < 12; ++k) {
        int t = reflect_i(2 * m3 + k - 10, 2056);
        float x = sL2[t - base2];
        alo += x * rec_lo_c(k); ahi += x * rec_hi_c(k);
      }
      lo_f[(size_t)seq * 1033 + m3] = alo;
      hseq[6157 + m3] = ahi;
    }
  }
}

// ---------------------------------------------------------------- DWT small: 1033->522->266->138->74->42 per seq
__device__ __forceinline__ void dwt_lvl(const float* in, int n, float* out, int outn, float* hg)
{
  for (int m = threadIdx.x; m < outn; m += 256) {
    float alo = 0.f, ahi = 0.f;
    #pragma unroll
    for (int k = 0; k < 12; ++k) {
      float x = in[reflect_i(2 * m + k - 10, n)];
      alo += x * rec_lo_c(k); ahi += x * rec_hi_c(k);
    }
    out[m] = alo; hg[m] = ahi;
  }
  __syncthreads();
}

__global__ __launch_bounds__(256) void dwt_small(
    const float* __restrict__ lo_f, float* __restrict__ highs, float* __restrict__ yl)
{
  __shared__ float A[1040], Bb[528];
  int seq = blockIdx.x;
  const float* src = lo_f + (size_t)seq * 1033;
  float* hseq = highs + (size_t)seq * HTOT;
  for (int i = threadIdx.x; i < 1033; i += 256) A[i] = src[i];
  __syncthreads();
  dwt_lvl(A, 1033, Bb, 522, hseq + 7190);
  dwt_lvl(Bb, 522, A, 266, hseq + 7712);
  dwt_lvl(A, 266, Bb, 138, hseq + 7978);
  dwt_lvl(Bb, 138, A, 74, hseq + 8116);
  dwt_lvl(A, 74, Bb, 42, hseq + 8190);
  for (int m = threadIdx.x; m < MODES; m += 256) yl[seq * MODES + m] = Bb[m];
}

// ---------------------------------------------------------------- coarse-band channel mix (yl and yh fused in one launch)
__global__ __launch_bounds__(256) void mix2(
    const float* __restrict__ yl_raw, const float* __restrict__ highs,
    const float* __restrict__ w1i, const float* __restrict__ w2i,
    float* __restrict__ yl_m, float* __restrict__ yh_m)
{
  bool hi = blockIdx.x >= 336;
  int idx = (blockIdx.x - (hi ? 336 : 0)) * 256 + threadIdx.x;
  if (idx >= 32 * 64 * MODES) return;
  int xx = idx % MODES;
  int o  = (idx / MODES) % 64;
  int b  = idx / (MODES * 64);
  const float* in = hi ? (highs + 8190) : yl_raw;
  size_t stride   = hi ? HTOT : MODES;
  const float* w  = hi ? w2i : w1i;
  float acc = 0.f;
  for (int i = 0; i < 64; ++i)
    acc += in[((size_t)(b * 64 + i)) * stride + xx] * w[(i * 64 + o) * MODES + xx];
  (hi ? yh_m : yl_m)[(b * 64 + o) * MODES + xx] = acc;
}

// ---------------------------------------------------------------- IDWT small: 42->...->1033 per seq (polyphase)
__device__ __forceinline__ void idwt_lvl(const float* lo, const float* h, float* out, int outn)
{
  const int par = threadIdx.x & 1;
  for (int m = threadIdx.x; m < outn; m += 256) {
    int t0 = (m - par) >> 1;
    float acc = 0.f;
    #pragma unroll
    for (int i = 0; i < 6; ++i) {
      float cl = par ? dec_lo_c(2 * i) : dec_lo_c(2 * i + 1);
      float ch = par ? dec_hi_c(2 * i) : dec_hi_c(2 * i + 1);
      acc += lo[t0 + i] * cl + h[t0 + i] * ch;
    }
    out[m] = acc;
  }
}

__device__ __forceinline__ void stage_band(float* dst, const float* src, int len, int alloc)
{
  for (int i = threadIdx.x; i < alloc; i += 256) dst[i] = (i < len) ? src[i] : 0.f;
}

__global__ __launch_bounds__(256) void idwt_small(
    const float* __restrict__ yl_m, const float* __restrict__ yh_m,
    const float* __restrict__ highs, float* __restrict__ lo_i)
{
  __shared__ float bands[1132];
  __shared__ float wa[1040], wb[528];
  int seq = blockIdx.x;
  const float* hseq = highs + (size_t)seq * HTOT;
  stage_band(bands + 0,   yl_m + (size_t)seq * MODES, 42, 50);
  stage_band(bands + 50,  yh_m + (size_t)seq * MODES, 42, 50);
  stage_band(bands + 100, hseq + 8116, 74, 82);
  stage_band(bands + 182, hseq + 7978, 138, 146);
  stage_band(bands + 328, hseq + 7712, 266, 274);
  stage_band(bands + 602, hseq + 7190, 522, 530);
  __syncthreads();
  idwt_lvl(bands + 0, bands + 50, wa, 74);    __syncthreads();
  idwt_lvl(wa, bands + 100, wb, 138);         __syncthreads();
  idwt_lvl(wb, bands + 182, wa, 266);         __syncthreads();
  idwt_lvl(wa, bands + 328, wb, 522);         __syncthreads();
  const int par = threadIdx.x & 1;
  for (int m = threadIdx.x; m < 1033; m += 256) {
    int t0 = (m - par) >> 1;
    float acc = 0.f;
    #pragma unroll
    for (int i = 0; i < 6; ++i) {
      float cl = par ? dec_lo_c(2 * i) : dec_lo_c(2 * i + 1);
      float ch = par ? dec_hi_c(2 * i) : dec_hi_c(2 * i + 1);
      acc += wb[t0 + i] * cl + bands[602 + t0 + i] * ch;
    }
    lo_i[(size_t)seq * 1033 + m] = acc;
  }
}

// ---------------------------------------------------------------- IDWT big: 1033->2056->4101->8192, 4 chunks/seq
__global__ __launch_bounds__(256) void idwt_big(
    const float* __restrict__ lo_i, const float* __restrict__ highs, float* __restrict__ x1)
{
  __shared__ float sL3[280], sH3[280], sL2[544], sH2[544], sL1[1040], sH1[1040];
  int seq = blockIdx.x >> 2, c = blockIdx.x & 3;
  const float* hseq = highs + (size_t)seq * HTOT;
  const float* l3   = lo_i + (size_t)seq * 1033;
  int b3 = 256 * c - 2, b2 = 512 * c - 2, b1 = 1024 * c - 2;
  const int par = threadIdx.x & 1;

  for (int i = threadIdx.x; i < 280; i += 256) {
    int g = b3 + i;
    bool ok = (g >= 0 && g < 1033);
    sL3[i] = ok ? l3[g] : 0.f;
    sH3[i] = ok ? hseq[6157 + g] : 0.f;
  }
  for (int i = threadIdx.x; i < 536; i += 256) {
    int g = b2 + i;
    sH2[i] = (g >= 0 && g < 2056) ? hseq[4101 + g] : 0.f;
  }
  for (int i = threadIdx.x; i < 1040; i += 256) {
    int g = b1 + i;
    sH1[i] = (g >= 0 && g < 4101) ? hseq[g] : 0.f;
  }
  __syncthreads();

  for (int u = threadIdx.x; u < 536; u += 256) {
    int m = b2 + u;
    int t0 = ((m - par) >> 1) - b3;
    float acc = 0.f;
    #pragma unroll
    for (int i = 0; i < 6; ++i) {
      float cl = par ? dec_lo_c(2 * i) : dec_lo_c(2 * i + 1);
      float ch = par ? dec_hi_c(2 * i) : dec_hi_c(2 * i + 1);
      acc += sL3[t0 + i] * cl + sH3[t0 + i] * ch;
    }
    sL2[u] = (m >= 0 && m < 2056) ? acc : 0.f;
  }
  __syncthreads();

  for (int u = threadIdx.x; u < 1040; u += 256) {
    int m = b1 + u;
    int t0 = ((m - par) >> 1) - b2;
    float acc = 0.f;
    #pragma unroll
    for (int i = 0; i < 6; ++i) {
      float cl = par ? dec_lo_c(2 * i) : dec_lo_c(2 * i + 1);
      float ch = par ? dec_hi_c(2 * i) : dec_hi_c(2 * i + 1);
      acc += sL2[t0 + i] * cl + sH2[t0 + i] * ch;
    }
    sL1[u] = (m >= 0 && m < 4101) ? acc : 0.f;
  }
  __syncthreads();

  for (int u = threadIdx.x; u < 2048; u += 256) {
    int m = 2048 * c + u;
    int t0 = ((m - par) >> 1) - b1;
    float acc = 0.f;
    #pragma unroll
    for (int i = 0; i < 6; ++i) {
      float cl = par ? dec_lo_c(2 * i) : dec_lo_c(2 * i + 1);
      float ch = par ? dec_hi_c(2 * i) : dec_hi_c(2 * i + 1);
      acc += sL1[t0 + i] * cl + sH1[t0 + i] * ch;
    }
    x1[(size_t)seq * S_LEN + m] = acc;
  }
}

// ---------------------------------------------------------------- layer pointwise via MFMA (split bf16, pre-split W)
__global__ __launch_bounds__(256) void pw_mfma(
    const float* __restrict__ x1, float* v,
    const u16* __restrict__ wcH, const u16* __restrict__ wcL,
    const float* __restrict__ cb, int do_gelu)
{
  __shared__ u16 aH[64][64], aL[64][64];   // A-tile [pos][ch] swizzled
  __shared__ u16 wH[64][64], wL[64][64];   // W^T   [o][ch]   swizzled (pre-split)
  __shared__ float cbl[64];
  int b  = blockIdx.x >> 7;
  int s0 = (blockIdx.x & 127) << 6;
  int t  = threadIdx.x;

  {  // linear vector copy of pre-swizzled weights: conflict-free
    const v8s* srcH = (const v8s*)wcH;
    const v8s* srcL = (const v8s*)wcL;
    v8s* dstH = (v8s*)&wH[0][0];
    v8s* dstL = (v8s*)&wL[0][0];
    #pragma unroll
    for (int r = 0; r < 2; ++r) {
      dstH[t + 256 * r] = srcH[t + 256 * r];
      dstL[t + 256 * r] = srcL[t + 256 * r];
    }
  }
  if (t < 64) cbl[t] = cb[t];

  #pragma unroll
  for (int r = 0; r < 4; ++r) {          // A stage: float4 loads
    int idx = t + 256 * r;               // 1024 float4s
    int ch = idx >> 4, p4 = (idx & 15) << 2;
    float4 xv = *(const float4*)&v[((size_t)(b * 64 + ch)) * S_LEN + s0 + p4];
    u16 h0 = bf16_rn(xv.x); aH[p4+0][ch ^ (((p4+0)&7)<<3)] = h0; aL[p4+0][ch ^ (((p4+0)&7)<<3)] = bf16_rn(xv.x - bf16_to_f(h0));
    u16 h1 = bf16_rn(xv.y); aH[p4+1][ch ^ (((p4+1)&7)<<3)] = h1; aL[p4+1][ch ^ (((p4+1)&7)<<3)] = bf16_rn(xv.y - bf16_to_f(h1));
    u16 h2 = bf16_rn(xv.z); aH[p4+2][ch ^ (((p4+2)&7)<<3)] = h2; aL[p4+2][ch ^ (((p4+2)&7)<<3)] = bf16_rn(xv.z - bf16_to_f(h2));
    u16 h3 = bf16_rn(xv.w); aH[p4+3][ch ^ (((p4+3)&7)<<3)] = h3; aL[p4+3][ch ^ (((p4+3)&7)<<3)] = bf16_rn(xv.w - bf16_to_f(h3));
  }
  __syncthreads();

  int l = t & 63, wv_ = t >> 6;        // 4 waves, each owns 16 pos
  int pi = l & 15, kg = l >> 4;
  int pos = wv_ * 16 + pi;
  int swz = (pi & 7) << 3;

  v4f acc[4];
  #pragma unroll
  for (int i = 0; i < 4; ++i) acc[i] = v4f{0.f, 0.f, 0.f, 0.f};

  #pragma unroll
  for (int kt = 0; kt < 2; ++kt) {
    int ka = (kg * 8 + kt * 32) ^ swz;
    v8s ah = *(const v8s*)&aH[pos][ka];
    v8s al = *(const v8s*)&aL[pos][ka];
    #pragma unroll
    for (int ct = 0; ct < 4; ++ct) {
      int o = ct * 16 + pi;
      v8s bh = *(const v8s*)&wH[o][ka];
      v8s bl = *(const v8s*)&wL[o][ka];
      acc[ct] = __builtin_amdgcn_mfma_f32_16x16x32_bf16(ah, bh, acc[ct], 0, 0, 0);
      acc[ct] = __builtin_amdgcn_mfma_f32_16x16x32_bf16(ah, bl, acc[ct], 0, 0, 0);
      acc[ct] = __builtin_amdgcn_mfma_f32_16x16x32_bf16(al, bh, acc[ct], 0, 0, 0);
    }
  }

  #pragma unroll
  for (int ct = 0; ct < 4; ++ct) {
    int o = ct * 16 + pi;
    size_t base = ((size_t)(b * 64 + o)) * S_LEN + s0 + wv_ * 16 + kg * 4;
    float4 x4 = *(const float4*)&x1[base];
    float cbv = cbl[o];
    float y0 = acc[ct][0] + x4.x + cbv;
    float y1 = acc[ct][1] + x4.y + cbv;
    float y2 = acc[ct][2] + x4.z + cbv;
    float y3 = acc[ct][3] + x4.w + cbv;
    if (do_gelu) { y0 = gelu_f(y0); y1 = gelu_f(y1); y2 = gelu_f(y2); y3 = gelu_f(y3); }
    float4 y4 = make_float4(y0, y1, y2, y3);
    *(float4*)&v[base] = y4;
  }
}

// ---------------------------------------------------------------- head via MFMA (pre-split W)
__global__ __launch_bounds__(256) void head_mfma(
    const float* __restrict__ v,
    const u16* __restrict__ whH, const u16* __restrict__ whL,
    const float* __restrict__ fc1b, const float* __restrict__ fc2w,
    const float* __restrict__ fc2b, float* __restrict__ out)
{
  __shared__ u16 aH[64][64], aL[64][64];     // A [pos][ch]
  __shared__ u16 wH[128][64], wL[128][64];   // fc1^T [j][ch] (pre-split)
  __shared__ float f1b[128], f2w[128];
  int b  = blockIdx.x >> 7;
  int s0 = (blockIdx.x & 127) << 6;
  int t  = threadIdx.x;

  {
    const v8s* srcH = (const v8s*)whH;
    const v8s* srcL = (const v8s*)whL;
    v8s* dstH = (v8s*)&wH[0][0];
    v8s* dstL = (v8s*)&wL[0][0];
    #pragma unroll
    for (int r = 0; r < 4; ++r) {
      dstH[t + 256 * r] = srcH[t + 256 * r];
      dstL[t + 256 * r] = srcL[t + 256 * r];
    }
  }
  if (t < 128) { f1b[t] = fc1b[t]; f2w[t] = fc2w[t]; }

  #pragma unroll
  for (int r = 0; r < 4; ++r) {
    int idx = t + 256 * r;
    int ch = idx >> 4, p4 = (idx & 15) << 2;
    float4 xv = *(const float4*)&v[((size_t)(b * 64 + ch)) * S_LEN + s0 + p4];
    u16 h0 = bf16_rn(xv.x); aH[p4+0][ch ^ (((p4+0)&7)<<3)] = h0; aL[p4+0][ch ^ (((p4+0)&7)<<3)] = bf16_rn(xv.x - bf16_to_f(h0));
    u16 h1 = bf16_rn(xv.y); aH[p4+1][ch ^ (((p4+1)&7)<<3)] = h1; aL[p4+1][ch ^ (((p4+1)&7)<<3)] = bf16_rn(xv.y - bf16_to_f(h1));
    u16 h2 = bf16_rn(xv.z); aH[p4+2][ch ^ (((p4+2)&7)<<3)] = h2; aL[p4+2][ch ^ (((p4+2)&7)<<3)] = bf16_rn(xv.z - bf16_to_f(h2));
    u16 h3 = bf16_rn(xv.w); aH[p4+3][ch ^ (((p4+3)&7)<<3)] = h3; aL[p4+3][ch ^ (((p4+3)&7)<<3)] = bf16_rn(xv.w - bf16_to_f(h3));
  }
  __syncthreads();

  int l = t & 63, wv_ = t >> 6;
  int pi = l & 15, kg = l >> 4;
  int pos = wv_ * 16 + pi;
  int swz = (pi & 7) << 3;

  v4f acc[8];
  #pragma unroll
  for (int i = 0; i < 8; ++i) acc[i] = v4f{0.f, 0.f, 0.f, 0.f};

  #pragma unroll
  for (int kt = 0; kt < 2; ++kt) {
    int ka = (kg * 8 + kt * 32) ^ swz;
    v8s ah = *(const v8s*)&aH[pos][ka];
    v8s al = *(const v8s*)&aL[pos][ka];
    #pragma unroll
    for (int ct = 0; ct < 8; ++ct) {
      int j = ct * 16 + pi;
      v8s bh = *(const v8s*)&wH[j][ka];
      v8s bl = *(const v8s*)&wL[j][ka];
      acc[ct] = __builtin_amdgcn_mfma_f32_16x16x32_bf16(ah, bh, acc[ct], 0, 0, 0);
      acc[ct] = __builtin_amdgcn_mfma_f32_16x16x32_bf16(ah, bl, acc[ct], 0, 0, 0);
      acc[ct] = __builtin_amdgcn_mfma_f32_16x16x32_bf16(al, bh, acc[ct], 0, 0, 0);
    }
  }

  float part[4] = {0.f, 0.f, 0.f, 0.f};
  #pragma unroll
  for (int ct = 0; ct < 8; ++ct) {
    int j = ct * 16 + pi;
    float bias = f1b[j], f2 = f2w[j];
    #pragma unroll
    for (int r = 0; r < 4; ++r) {
      float d = acc[ct][r] + bias;
      part[r] += f2 * gelu_f(d);
    }
  }
  #pragma unroll
  for (int r = 0; r < 4; ++r) {
    part[r] += __shfl_xor(part[r], 1, 16);
    part[r] += __shfl_xor(part[r], 2, 16);
    part[r] += __shfl_xor(part[r], 4, 16);
    part[r] += __shfl_xor(part[r], 8, 16);
  }
  if (pi == 0) {
    float b2 = fc2b[0];
    float4 o4 = make_float4(part[0] + b2, part[1] + b2, part[2] + b2, part[3] + b2);
    *(float4*)&out[(size_t)b * S_LEN + s0 + wv_ * 16 + kg * 4] = o4;
  }
}

// ----------------------------------------------------------------
extern "C" void kernel_launch(void* const* d_in, const int* in_sizes, int n_in,
                              void* d_out, int out_size, void* d_ws, size_t ws_size,
                              hipStream_t stream) {
  const float* x    = (const float*)d_in[0];
  const float* fc0w = (const float*)d_in[1];
  const float* fc0b = (const float*)d_in[2];
  const float* w1   = (const float*)d_in[3];
  const float* w2   = (const float*)d_in[4];
  const float* cw   = (const float*)d_in[5];
  const float* cb   = (const float*)d_in[6];
  const float* fc1w = (const float*)d_in[7];
  const float* fc1b = (const float*)d_in[8];
  const float* fc2w = (const float*)d_in[9];
  const float* fc2b = (const float*)d_in[10];
  float* out = (float*)d_out;

  float* ws     = (float*)d_ws;
  float* v      = ws;
  float* x1     = v      + (size_t)BC * S_LEN;
  float* highs  = x1     + (size_t)BC * S_LEN;
  float* yl_raw = highs  + (size_t)BC * HTOT;
  float* yl_m   = yl_raw + (size_t)BC * MODES;
  float* yh_m   = yl_m   + (size_t)BC * MODES;
  float* lo_f   = yh_m   + (size_t)BC * MODES;
  float* lo_i   = lo_f   + (size_t)BC * 1033;
  u16*   whH    = (u16*)(lo_i + (size_t)BC * 1033);
  u16*   whL    = whH + 8192;
  u16*   wcH    = whL + 8192;
  u16*   wcL    = wcH + 16384;
  size_t needed = (size_t)((char*)(wcL + 16384) - (char*)ws);
  if (ws_size < needed) return;

  prep_split<<<96, 256, 0, stream>>>(fc1w, cw, whH, whL, wcH, wcL);
  fc0_kernel<<<1024, 256, 0, stream>>>(x, fc0w, fc0b, v);

  for (int i = 0; i < 4; ++i) {
    dwt_big<<<BC * 4, 256, 0, stream>>>(v, highs, lo_f);
    dwt_small<<<BC, 256, 0, stream>>>(lo_f, highs, yl_raw);
    mix2<<<672, 256, 0, stream>>>(yl_raw, highs, w1 + (size_t)i * 64 * 64 * MODES,
                                  w2 + (size_t)i * 64 * 64 * MODES, yl_m, yh_m);
    idwt_small<<<BC, 256, 0, stream>>>(yl_m, yh_m, highs, lo_i);
    idwt_big<<<BC * 4, 256, 0, stream>>>(lo_i, highs, x1);
    pw_mfma<<<4096, 256, 0, stream>>>(x1, v, wcH + i * 4096, wcL + i * 4096, cb + i * 64, (i < 3) ? 1 : 0);
  }

  head_mfma<<<4096, 256, 0, stream>>>(v, whH, whL, fc1b, fc2w, fc2b, out);
}

// Round 8
// 610.113 us; speedup vs baseline: 3.0248x; 1.0511x over previous
//
#include <hip/hip_runtime.h>
#include <cmath>

#define BC 2048          // B*W sequences
#define S_LEN 8192
#define MODES 42
// padded pyramid: L1@0(4101) L2@4104(2056) L3@6160(1033) L4@7196(522)
//                 L5@7720(266) L6@7988(138) L7@8128(74) L8@8204(42)
#define HTOT 8248
#define LO_STR 1036      // padded stride for the 1033-long lo buffers

static constexpr float C_LO[12] = {
  0.11154074335008017f, 0.4946238903983854f, 0.7511339080215775f,
  0.3152503517092432f, -0.22626469396516913f, -0.12976686756709563f,
  0.09750160558707936f, 0.02752286553001629f, -0.031582039318031156f,
  0.0005538422009938016f, 0.004777257511010651f, -0.00107730108499558f };

__device__ __forceinline__ float rec_lo_c(int k){ return C_LO[k]; }
__device__ __forceinline__ float rec_hi_c(int k){ float v = C_LO[11-k]; return (k&1)? -v : v; }
__device__ __forceinline__ float dec_lo_c(int k){ return C_LO[11-k]; }
__device__ __forceinline__ float dec_hi_c(int k){ float v = C_LO[k];    return (k&1)?  v : -v; }

// branchless erf (Abramowitz-Stegun 7.1.26, |err|<=1.5e-7)
__device__ __forceinline__ float erf_fast(float x){
  float ax = fabsf(x);
  float t  = __fdividef(1.0f, 1.0f + 0.3275911f * ax);
  float p  = ((((1.061405429f * t - 1.453152027f) * t) + 1.421413741f) * t - 0.284496736f) * t + 0.254829592f;
  float y  = 1.0f - p * t * __expf(-ax * ax);
  return copysignf(y, x);
}
__device__ __forceinline__ float gelu_f(float x){
  return 0.5f * x * (1.0f + erf_fast(x * 0.70710678118654752440f));
}

__device__ __forceinline__ int reflect_i(int t, int n){
  t = (t < 0) ? (-1 - t) : t;
  t = (t >= n) ? (2 * n - 1 - t) : t;
  return t;
}

__device__ __forceinline__ unsigned short bf16_rn(float x){
  unsigned int b = __float_as_uint(x);
  b += 0x7FFF + ((b >> 16) & 1);
  return (unsigned short)(b >> 16);
}
__device__ __forceinline__ float bf16_to_f(unsigned short h){
  return __uint_as_float(((unsigned int)h) << 16);
}

typedef short  v8s __attribute__((ext_vector_type(8)));
typedef float  v4f __attribute__((ext_vector_type(4)));
typedef unsigned short u16;

__device__ __forceinline__ void ld3f4(float* w, const float* s){
  *(float4*)&w[0] = *(const float4*)&s[0];
  *(float4*)&w[4] = *(const float4*)&s[4];
  *(float4*)&w[8] = *(const float4*)&s[8];
}
__device__ __forceinline__ void ld5f4(float* w, const float* s){
  *(float4*)&w[0]  = *(const float4*)&s[0];
  *(float4*)&w[4]  = *(const float4*)&s[4];
  *(float4*)&w[8]  = *(const float4*)&s[8];
  *(float4*)&w[12] = *(const float4*)&s[12];
  *(float4*)&w[16] = *(const float4*)&s[16];
}

// zero-pad staging: dst[j] = (0<=g0+j<n) ? src[g0+j] : 0 ; g0%4==0, cnt%4==0
__device__ __forceinline__ void stage_g(float* dst, const float* src, int g0, int cnt, int n){
  for (int j4 = threadIdx.x; j4 < (cnt >> 2); j4 += 256) {
    int g = g0 + 4 * j4;
    float4 val;
    if (g >= 0 && g + 3 < n) val = *(const float4*)&src[g];
    else {
      val.x = (g   >= 0 && g   < n) ? src[g]   : 0.f;
      val.y = (g+1 >= 0 && g+1 < n) ? src[g+1] : 0.f;
      val.z = (g+2 >= 0 && g+2 < n) ? src[g+2] : 0.f;
      val.w = (g+3 >= 0 && g+3 < n) ? src[g+3] : 0.f;
    }
    *(float4*)&dst[4*j4] = val;
  }
}

// polyphase IDWT taps for output d (d compile-time in unrolled loops)
template<int OFF>
__device__ __forceinline__ float idwt_tap(const float* wl, const float* wh, int d){
  float acc = 0.f;
  int t = OFF + (d >> 1);
  if (d & 1) {
    #pragma unroll
    for (int i = 0; i < 6; ++i) acc += wl[t+i]*dec_lo_c(2*i)   + wh[t+i]*dec_hi_c(2*i);
  } else {
    #pragma unroll
    for (int i = 0; i < 6; ++i) acc += wl[t+i]*dec_lo_c(2*i+1) + wh[t+i]*dec_hi_c(2*i+1);
  }
  return acc;
}

// ---------------------------------------------------------------- prep: split weights to hi/lo bf16 in swizzled layout
__global__ __launch_bounds__(256) void prep_split(
    const float* __restrict__ fc1w, const float* __restrict__ cw,
    u16* __restrict__ whH, u16* __restrict__ whL,
    u16* __restrict__ wcH, u16* __restrict__ wcL)
{
  int i = blockIdx.x * 256 + threadIdx.x;
  if (i < 8192) {
    int c = i >> 7, j = i & 127;
    float wv = fc1w[i];
    u16 h = bf16_rn(wv);
    float lo = wv - bf16_to_f(h);
    int cs = c ^ ((j & 7) << 3);
    whH[j * 64 + cs] = h; whL[j * 64 + cs] = bf16_rn(lo);
  }
  int k = i - 8192;
  if (k >= 0 && k < 16384) {
    int l = k >> 12, r = k & 4095;
    int c = r >> 6, o = r & 63;
    float wv = cw[k];
    u16 h = bf16_rn(wv);
    float lo = wv - bf16_to_f(h);
    int cs = c ^ ((o & 7) << 3);
    wcH[l * 4096 + o * 64 + cs] = h; wcL[l * 4096 + o * 64 + cs] = bf16_rn(lo);
  }
}

// ---------------------------------------------------------------- fc0
__global__ __launch_bounds__(256) void fc0_kernel(
    const float* __restrict__ x, const float* __restrict__ w,
    const float* __restrict__ bias, float* __restrict__ v)
{
  int p = blockIdx.x * 256 + threadIdx.x;
  int b = p >> 13, s = p & 8191;
  float xv = x[p];
  float g  = (float)s * (1.0f / 8191.0f);
  for (int c = 0; c < 64; ++c) {
    v[((size_t)(b * 64 + c)) * S_LEN + s] = xv * w[c] + g * w[64 + c] + bias[c];
  }
}

// ---------------------------------------------------------------- DWT big: 8192->4101->2056->1033, 4 chunks/seq
__global__ __launch_bounds__(256) void dwt_big(
    const float* __restrict__ vin, float* __restrict__ highs, float* __restrict__ lo_f)
{
  __shared__ alignas(16) float sV[2184], sL1[1088], sL2[544];
  int seq = blockIdx.x >> 2, c = blockIdx.x & 3;
  const float* src = vin + (size_t)seq * S_LEN;
  float* hseq = highs + (size_t)seq * HTOT;
  int tid = threadIdx.x;

  // stage sV[j] = src[reflect(g0+j)], g0 = 2080c-72 (mult of 4), 2180 floats
  int g0 = 2080 * c - 72;
  for (int j4 = tid; j4 < 545; j4 += 256) {
    int g = g0 + 4 * j4;
    float4 val;
    if (g >= 0 && g + 3 < 8192) val = *(const float4*)&src[g];
    else {
      val.x = src[reflect_i(g,   8192)];
      val.y = src[reflect_i(g+1, 8192)];
      val.z = src[reflect_i(g+2, 8192)];
      val.w = src[reflect_i(g+3, 8192)];
    }
    *(float4*)&sV[4*j4] = val;
  }
  __syncthreads();

  int base1 = 1040 * c - 30;
  // L1: u in [0,1082), m1 = base1+u, taps sV[2u+2+k]
  for (int u0 = 4*tid; u0 < 1082; u0 += 1024) {
    float w[20];
    ld5f4(w, &sV[2*u0]);
    #pragma unroll
    for (int d = 0; d < 4; ++d) {
      if (u0 + d < 1082) {
        float alo = 0.f, ahi = 0.f;
        #pragma unroll
        for (int k = 0; k < 12; ++k) {
          float x = w[2*d + 2 + k];
          alo += x * rec_lo_c(k); ahi += x * rec_hi_c(k);
        }
        sL1[u0+d] = alo;
        int m1 = base1 + u0 + d;
        if (m1 >= 1040*c && m1 < 1040*c + 1040 && m1 >= 0 && m1 < 4101) hseq[m1] = ahi;
      }
    }
  }
  __syncthreads();
  // reflect fixups so L2 can read linearly
  if (c == 0) { for (int u = tid;        u < 30;   u += 256) sL1[u] = sL1[59 - u]; }
  if (c == 3) { for (int u = 1011 + tid; u < 1082; u += 256) sL1[u] = sL1[2021 - u]; }
  __syncthreads();

  int base2 = 520 * c - 10;
  // L2: u in [0,534), taps sL1[2u+k]
  for (int u0 = 4*tid; u0 < 534; u0 += 1024) {
    float w[20];
    ld5f4(w, &sL1[2*u0]);
    #pragma unroll
    for (int d = 0; d < 4; ++d) {
      if (u0 + d < 534) {
        float alo = 0.f, ahi = 0.f;
        #pragma unroll
        for (int k = 0; k < 12; ++k) {
          float x = w[2*d + k];
          alo += x * rec_lo_c(k); ahi += x * rec_hi_c(k);
        }
        sL2[u0+d] = alo;
        int m2 = base2 + u0 + d;
        if (m2 >= 520*c && m2 < 520*c + 520 && m2 >= 0 && m2 < 2056) hseq[4104 + m2] = ahi;
      }
    }
  }
  __syncthreads();
  if (c == 0) { for (int u = tid;       u < 10;  u += 256) sL2[u] = sL2[19 - u]; }
  if (c == 3) { for (int u = 506 + tid; u < 534; u += 256) sL2[u] = sL2[1011 - u]; }
  __syncthreads();

  // L3: u in [0,260), m3 = 260c+u, taps sL2[2u+k]
  for (int u0 = 4*tid; u0 < 260; u0 += 1024) {
    float w[20];
    ld5f4(w, &sL2[2*u0]);
    #pragma unroll
    for (int d = 0; d < 4; ++d) {
      int m3 = 260*c + u0 + d;
      if (u0 + d < 260 && m3 < 1033) {
        float alo = 0.f, ahi = 0.f;
        #pragma unroll
        for (int k = 0; k < 12; ++k) {
          float x = w[2*d + k];
          alo += x * rec_lo_c(k); ahi += x * rec_hi_c(k);
        }
        lo_f[(size_t)seq * LO_STR + m3] = alo;
        hseq[6160 + m3] = ahi;
      }
    }
  }
}

// ---------------------------------------------------------------- DWT small: 1033->522->266->138->74->42 per seq
__device__ __forceinline__ void dwt_lvl_v(const float* in, int n, float* out, int outn, float* hg)
{
  for (int u0 = 4*(int)threadIdx.x; u0 < outn; u0 += 1024) {
    bool fast = (u0 >= 8) && (2*u0 + 7 < n) && (u0 + 3 < outn);
    if (fast) {
      float w[20];
      ld5f4(w, &in[2*u0 - 12]);
      #pragma unroll
      for (int d = 0; d < 4; ++d) {
        float alo = 0.f, ahi = 0.f;
        #pragma unroll
        for (int k = 0; k < 12; ++k) {
          float x = w[2*d + 2 + k];
          alo += x * rec_lo_c(k); ahi += x * rec_hi_c(k);
        }
        out[u0+d] = alo; hg[u0+d] = ahi;
      }
    } else {
      for (int d = 0; d < 4; ++d) {
        if (u0 + d < outn) {
          float alo = 0.f, ahi = 0.f;
          #pragma unroll
          for (int k = 0; k < 12; ++k) {
            float x = in[reflect_i(2*(u0+d) + k - 10, n)];
            alo += x * rec_lo_c(k); ahi += x * rec_hi_c(k);
          }
          out[u0+d] = alo; hg[u0+d] = ahi;
        }
      }
    }
  }
  __syncthreads();
}

__global__ __launch_bounds__(256) void dwt_small(
    const float* __restrict__ lo_f, float* __restrict__ highs, float* __restrict__ yl)
{
  __shared__ alignas(16) float A[1040], Bb[528];
  int seq = blockIdx.x;
  const float* src = lo_f + (size_t)seq * LO_STR;
  float* hseq = highs + (size_t)seq * HTOT;
  for (int i = 4*(int)threadIdx.x; i < 1033; i += 1024) {
    if (i + 3 < 1033) *(float4*)&A[i] = *(const float4*)&src[i];
    else { for (int d = 0; d < 4; ++d) if (i + d < 1033) A[i+d] = src[i+d]; }
  }
  __syncthreads();
  dwt_lvl_v(A, 1033, Bb, 522, hseq + 7196);
  dwt_lvl_v(Bb, 522, A, 266, hseq + 7720);
  dwt_lvl_v(A, 266, Bb, 138, hseq + 7988);
  dwt_lvl_v(Bb, 138, A, 74,  hseq + 8128);
  dwt_lvl_v(A, 74,  Bb, 42,  hseq + 8204);
  for (int m = threadIdx.x; m < MODES; m += 256) yl[seq * MODES + m] = Bb[m];
}

// ---------------------------------------------------------------- coarse-band channel mix (yl + yh in one launch)
__global__ __launch_bounds__(256) void mix2(
    const float* __restrict__ yl_raw, const float* __restrict__ highs,
    const float* __restrict__ w1i, const float* __restrict__ w2i,
    float* __restrict__ yl_m, float* __restrict__ yh_m)
{
  bool hi = blockIdx.x >= 336;
  int idx = (blockIdx.x - (hi ? 336 : 0)) * 256 + threadIdx.x;
  if (idx >= 32 * 64 * MODES) return;
  int xx = idx % MODES;
  int o  = (idx / MODES) % 64;
  int b  = idx / (MODES * 64);
  const float* in = hi ? (highs + 8204) : yl_raw;
  size_t stride   = hi ? HTOT : MODES;
  const float* w  = hi ? w2i : w1i;
  float acc = 0.f;
  for (int i = 0; i < 64; ++i)
    acc += in[((size_t)(b * 64 + i)) * stride + xx] * w[(i * 64 + o) * MODES + xx];
  (hi ? yh_m : yl_m)[(b * 64 + o) * MODES + xx] = acc;
}

// ---------------------------------------------------------------- IDWT small: 42->...->1033 per seq
__device__ __forceinline__ void idwt_lvl8(const float* lo, const float* h, float* out, int outn)
{
  for (int u0 = 8*(int)threadIdx.x; u0 < outn; u0 += 2048) {
    int ib = u0 >> 1;                 // 4*tid, 16B aligned
    float wl[12], wh[12];
    ld3f4(wl, &lo[ib]); ld3f4(wh, &h[ib]);
    #pragma unroll
    for (int d = 0; d < 8; ++d)
      if (u0 + d < outn) out[u0+d] = idwt_tap<0>(wl, wh, d);
  }
  __syncthreads();
}

__device__ __forceinline__ void stage_band(float* dst, const float* src, int len, int alloc)
{
  for (int i = threadIdx.x; i < alloc; i += 256) dst[i] = (i < len) ? src[i] : 0.f;
}

__global__ __launch_bounds__(256) void idwt_small(
    const float* __restrict__ yl_m, const float* __restrict__ yh_m,
    const float* __restrict__ highs, float* __restrict__ lo_i)
{
  // bands: yl@0(48) yh@48(48) h74@96(80) h138@176(144) h266@320(272) h522@592(528)
  __shared__ alignas(16) float bands[1120], wa[272], wb[528];
  int seq = blockIdx.x;
  const float* hseq = highs + (size_t)seq * HTOT;
  stage_band(bands + 0,   yl_m + (size_t)seq * MODES, 42, 48);
  stage_band(bands + 48,  yh_m + (size_t)seq * MODES, 42, 48);
  stage_band(bands + 96,  hseq + 8128, 74, 80);
  stage_band(bands + 176, hseq + 7988, 138, 144);
  stage_band(bands + 320, hseq + 7720, 266, 272);
  stage_band(bands + 592, hseq + 7196, 522, 528);
  __syncthreads();
  idwt_lvl8(bands + 0,  bands + 48,  wa, 74);
  idwt_lvl8(wa,         bands + 96,  wb, 138);
  idwt_lvl8(wb,         bands + 176, wa, 266);
  idwt_lvl8(wa,         bands + 320, wb, 522);
  // final: 522 -> 1033 (keep 1033), to global
  for (int u0 = 8*(int)threadIdx.x; u0 < 1033; u0 += 2048) {
    int ib = u0 >> 1;
    float wl[12], wh[12];
    ld3f4(wl, &wb[ib]); ld3f4(wh, &bands[592 + ib]);
    float o[8];
    #pragma unroll
    for (int d = 0; d < 8; ++d) o[d] = idwt_tap<0>(wl, wh, d);
    float* dst = lo_i + (size_t)seq * LO_STR + u0;
    if (u0 + 7 < 1033) {
      *(float4*)&dst[0] = make_float4(o[0], o[1], o[2], o[3]);
      *(float4*)&dst[4] = make_float4(o[4], o[5], o[6], o[7]);
    } else {
      for (int d = 0; d < 8; ++d) if (u0 + d < 1033) dst[d] = o[d];
    }
  }
}

// ---------------------------------------------------------------- IDWT big: 1033->2056->4101->8192, 4 chunks/seq
__global__ __launch_bounds__(256) void idwt_big(
    const float* __restrict__ lo_i, const float* __restrict__ highs, float* __restrict__ x1)
{
  __shared__ alignas(16) float sL3[288], sH3[288], sL2[544], sH2[544], sL1[1048], sH1[1048];
  int seq = blockIdx.x >> 2, c = blockIdx.x & 3;
  const float* hseq = highs + (size_t)seq * HTOT;
  const float* l3   = lo_i + (size_t)seq * LO_STR;
  int g3 = 256*c - 4, g2 = 512*c - 4, g1 = 1024*c - 4;   // aligned staging bases

  stage_g(sL3, l3,          g3, 288, 1033);
  stage_g(sH3, hseq + 6160, g3, 288, 1033);
  stage_g(sH2, hseq + 4104, g2, 544, 2056);
  stage_g(sH1, hseq,        g1, 1048, 4101);
  __syncthreads();

  // s5: produce lo2 values for m = (512c-2)+u0+d into sL2[m-g2]
  for (int u0 = 8*(int)threadIdx.x; u0 < 536; u0 += 2048) {
    int ib = u0 >> 1;                 // window base; tap offset 3
    float wl[12], wh[12];
    ld3f4(wl, &sL3[ib]); ld3f4(wh, &sH3[ib]);
    #pragma unroll
    for (int d = 0; d < 8; ++d) {
      if (u0 + d < 536) {
        int m = 512*c - 2 + u0 + d;
        float acc = idwt_tap<3>(wl, wh, d);
        sL2[u0 + d + 2] = (m >= 0 && m < 2056) ? acc : 0.f;
      }
    }
  }
  __syncthreads();

  // s6: produce lo1 values for m = (1024c-2)+u0+d into sL1[m-g1]
  for (int u0 = 8*(int)threadIdx.x; u0 < 1040; u0 += 2048) {
    int ib = u0 >> 1;
    float wl[12], wh[12];
    ld3f4(wl, &sL2[ib]); ld3f4(wh, &sH2[ib]);
    #pragma unroll
    for (int d = 0; d < 8; ++d) {
      if (u0 + d < 1040) {
        int m = 1024*c - 2 + u0 + d;
        float acc = idwt_tap<3>(wl, wh, d);
        sL1[u0 + d + 2] = (m >= 0 && m < 4101) ? acc : 0.f;
      }
    }
  }
  __syncthreads();

  // s7: outputs m = 2048c + u0 + d, exactly 2048 per chunk
  {
    int u0 = 8*(int)threadIdx.x;
    int ib = (u0 >> 1) + 4;
    float wl[12], wh[12];
    ld3f4(wl, &sL1[ib]); ld3f4(wh, &sH1[ib]);
    float o[8];
    #pragma unroll
    for (int d = 0; d < 8; ++d) o[d] = idwt_tap<0>(wl, wh, d);
    float* dst = x1 + (size_t)seq * S_LEN + 2048*c + u0;
    *(float4*)&dst[0] = make_float4(o[0], o[1], o[2], o[3]);
    *(float4*)&dst[4] = make_float4(o[4], o[5], o[6], o[7]);
  }
}

// ---------------------------------------------------------------- layer pointwise via MFMA (split bf16, pre-split W)
__global__ __launch_bounds__(256) void pw_mfma(
    const float* __restrict__ x1, float* v,
    const u16* __restrict__ wcH, const u16* __restrict__ wcL,
    const float* __restrict__ cb, int do_gelu)
{
  __shared__ u16 aH[64][64], aL[64][64];
  __shared__ u16 wH[64][64], wL[64][64];
  __shared__ float cbl[64];
  int b  = blockIdx.x >> 7;
  int s0 = (blockIdx.x & 127) << 6;
  int t  = threadIdx.x;

  {
    const v8s* srcH = (const v8s*)wcH;
    const v8s* srcL = (const v8s*)wcL;
    v8s* dstH = (v8s*)&wH[0][0];
    v8s* dstL = (v8s*)&wL[0][0];
    #pragma unroll
    for (int r = 0; r < 2; ++r) {
      dstH[t + 256 * r] = srcH[t + 256 * r];
      dstL[t + 256 * r] = srcL[t + 256 * r];
    }
  }
  if (t < 64) cbl[t] = cb[t];

  #pragma unroll
  for (int r = 0; r < 4; ++r) {
    int idx = t + 256 * r;
    int ch = idx >> 4, p4 = (idx & 15) << 2;
    float4 xv = *(const float4*)&v[((size_t)(b * 64 + ch)) * S_LEN + s0 + p4];
    u16 h0 = bf16_rn(xv.x); aH[p4+0][ch ^ (((p4+0)&7)<<3)] = h0; aL[p4+0][ch ^ (((p4+0)&7)<<3)] = bf16_rn(xv.x - bf16_to_f(h0));
    u16 h1 = bf16_rn(xv.y); aH[p4+1][ch ^ (((p4+1)&7)<<3)] = h1; aL[p4+1][ch ^ (((p4+1)&7)<<3)] = bf16_rn(xv.y - bf16_to_f(h1));
    u16 h2 = bf16_rn(xv.z); aH[p4+2][ch ^ (((p4+2)&7)<<3)] = h2; aL[p4+2][ch ^ (((p4+2)&7)<<3)] = bf16_rn(xv.z - bf16_to_f(h2));
    u16 h3 = bf16_rn(xv.w); aH[p4+3][ch ^ (((p4+3)&7)<<3)] = h3; aL[p4+3][ch ^ (((p4+3)&7)<<3)] = bf16_rn(xv.w - bf16_to_f(h3));
  }
  __syncthreads();

  int l = t & 63, wv_ = t >> 6;
  int pi = l & 15, kg = l >> 4;
  int pos = wv_ * 16 + pi;
  int swz = (pi & 7) << 3;

  v4f acc[4];
  #pragma unroll
  for (int i = 0; i < 4; ++i) acc[i] = v4f{0.f, 0.f, 0.f, 0.f};

  #pragma unroll
  for (int kt = 0; kt < 2; ++kt) {
    int ka = (kg * 8 + kt * 32) ^ swz;
    v8s ah = *(const v8s*)&aH[pos][ka];
    v8s al = *(const v8s*)&aL[pos][ka];
    #pragma unroll
    for (int ct = 0; ct < 4; ++ct) {
      int o = ct * 16 + pi;
      v8s bh = *(const v8s*)&wH[o][ka];
      v8s bl = *(const v8s*)&wL[o][ka];
      acc[ct] = __builtin_amdgcn_mfma_f32_16x16x32_bf16(ah, bh, acc[ct], 0, 0, 0);
      acc[ct] = __builtin_amdgcn_mfma_f32_16x16x32_bf16(ah, bl, acc[ct], 0, 0, 0);
      acc[ct] = __builtin_amdgcn_mfma_f32_16x16x32_bf16(al, bh, acc[ct], 0, 0, 0);
    }
  }

  #pragma unroll
  for (int ct = 0; ct < 4; ++ct) {
    int o = ct * 16 + pi;
    size_t base = ((size_t)(b * 64 + o)) * S_LEN + s0 + wv_ * 16 + kg * 4;
    float4 x4 = *(const float4*)&x1[base];
    float cbv = cbl[o];
    float y0 = acc[ct][0] + x4.x + cbv;
    float y1 = acc[ct][1] + x4.y + cbv;
    float y2 = acc[ct][2] + x4.z + cbv;
    float y3 = acc[ct][3] + x4.w + cbv;
    if (do_gelu) { y0 = gelu_f(y0); y1 = gelu_f(y1); y2 = gelu_f(y2); y3 = gelu_f(y3); }
    float4 y4 = make_float4(y0, y1, y2, y3);
    *(float4*)&v[base] = y4;
  }
}

// ---------------------------------------------------------------- head via MFMA (pre-split W)
__global__ __launch_bounds__(256) void head_mfma(
    const float* __restrict__ v,
    const u16* __restrict__ whH, const u16* __restrict__ whL,
    const float* __restrict__ fc1b, const float* __restrict__ fc2w,
    const float* __restrict__ fc2b, float* __restrict__ out)
{
  __shared__ u16 aH[64][64], aL[64][64];
  __shared__ u16 wH[128][64], wL[128][64];
  __shared__ float f1b[128], f2w[128];
  int b  = blockIdx.x >> 7;
  int s0 = (blockIdx.x & 127) << 6;
  int t  = threadIdx.x;

  {
    const v8s* srcH = (const v8s*)whH;
    const v8s* srcL = (const v8s*)whL;
    v8s* dstH = (v8s*)&wH[0][0];
    v8s* dstL = (v8s*)&wL[0][0];
    #pragma unroll
    for (int r = 0; r < 4; ++r) {
      dstH[t + 256 * r] = srcH[t + 256 * r];
      dstL[t + 256 * r] = srcL[t + 256 * r];
    }
  }
  if (t < 128) { f1b[t] = fc1b[t]; f2w[t] = fc2w[t]; }

  #pragma unroll
  for (int r = 0; r < 4; ++r) {
    int idx = t + 256 * r;
    int ch = idx >> 4, p4 = (idx & 15) << 2;
    float4 xv = *(const float4*)&v[((size_t)(b * 64 + ch)) * S_LEN + s0 + p4];
    u16 h0 = bf16_rn(xv.x); aH[p4+0][ch ^ (((p4+0)&7)<<3)] = h0; aL[p4+0][ch ^ (((p4+0)&7)<<3)] = bf16_rn(xv.x - bf16_to_f(h0));
    u16 h1 = bf16_rn(xv.y); aH[p4+1][ch ^ (((p4+1)&7)<<3)] = h1; aL[p4+1][ch ^ (((p4+1)&7)<<3)] = bf16_rn(xv.y - bf16_to_f(h1));
    u16 h2 = bf16_rn(xv.z); aH[p4+2][ch ^ (((p4+2)&7)<<3)] = h2; aL[p4+2][ch ^ (((p4+2)&7)<<3)] = bf16_rn(xv.z - bf16_to_f(h2));
    u16 h3 = bf16_rn(xv.w); aH[p4+3][ch ^ (((p4+3)&7)<<3)] = h3; aL[p4+3][ch ^ (((p4+3)&7)<<3)] = bf16_rn(xv.w - bf16_to_f(h3));
  }
  __syncthreads();

  int l = t & 63, wv_ = t >> 6;
  int pi = l & 15, kg = l >> 4;
  int pos = wv_ * 16 + pi;
  int swz = (pi & 7) << 3;

  v4f acc[8];
  #pragma unroll
  for (int i = 0; i < 8; ++i) acc[i] = v4f{0.f, 0.f, 0.f, 0.f};

  #pragma unroll
  for (int kt = 0; kt < 2; ++kt) {
    int ka = (kg * 8 + kt * 32) ^ swz;
    v8s ah = *(const v8s*)&aH[pos][ka];
    v8s al = *(const v8s*)&aL[pos][ka];
    #pragma unroll
    for (int ct = 0; ct < 8; ++ct) {
      int j = ct * 16 + pi;
      v8s bh = *(const v8s*)&wH[j][ka];
      v8s bl = *(const v8s*)&wL[j][ka];
      acc[ct] = __builtin_amdgcn_mfma_f32_16x16x32_bf16(ah, bh, acc[ct], 0, 0, 0);
      acc[ct] = __builtin_amdgcn_mfma_f32_16x16x32_bf16(ah, bl, acc[ct], 0, 0, 0);
      acc[ct] = __builtin_amdgcn_mfma_f32_16x16x32_bf16(al, bh, acc[ct], 0, 0, 0);
    }
  }

  float part[4] = {0.f, 0.f, 0.f, 0.f};
  #pragma unroll
  for (int ct = 0; ct < 8; ++ct) {
    int j = ct * 16 + pi;
    float bias = f1b[j], f2 = f2w[j];
    #pragma unroll
    for (int r = 0; r < 4; ++r) {
      float d = acc[ct][r] + bias;
      part[r] += f2 * gelu_f(d);
    }
  }
  #pragma unroll
  for (int r = 0; r < 4; ++r) {
    part[r] += __shfl_xor(part[r], 1, 16);
    part[r] += __shfl_xor(part[r], 2, 16);
    part[r] += __shfl_xor(part[r], 4, 16);
    part[r] += __shfl_xor(part[r], 8, 16);
  }
  if (pi == 0) {
    float b2 = fc2b[0];
    float4 o4 = make_float4(part[0] + b2, part[1] + b2, part[2] + b2, part[3] + b2);
    *(float4*)&out[(size_t)b * S_LEN + s0 + wv_ * 16 + kg * 4] = o4;
  }
}

// ----------------------------------------------------------------
extern "C" void kernel_launch(void* const* d_in, const int* in_sizes, int n_in,
                              void* d_out, int out_size, void* d_ws, size_t ws_size,
                              hipStream_t stream) {
  const float* x    = (const float*)d_in[0];
  const float* fc0w = (const float*)d_in[1];
  const float* fc0b = (const float*)d_in[2];
  const float* w1   = (const float*)d_in[3];
  const float* w2   = (const float*)d_in[4];
  const float* cw   = (const float*)d_in[5];
  const float* cb   = (const float*)d_in[6];
  const float* fc1w = (const float*)d_in[7];
  const float* fc1b = (const float*)d_in[8];
  const float* fc2w = (const float*)d_in[9];
  const float* fc2b = (const float*)d_in[10];
  float* out = (float*)d_out;

  float* ws     = (float*)d_ws;
  float* v      = ws;
  float* x1     = v      + (size_t)BC * S_LEN;
  float* highs  = x1     + (size_t)BC * S_LEN;
  float* yl_raw = highs  + (size_t)BC * HTOT;
  float* yl_m   = yl_raw + (size_t)BC * MODES;
  float* yh_m   = yl_m   + (size_t)BC * MODES;
  float* lo_f   = yh_m   + (size_t)BC * MODES;
  float* lo_i   = lo_f   + (size_t)BC * LO_STR;
  u16*   whH    = (u16*)(lo_i + (size_t)BC * LO_STR);
  u16*   whL    = whH + 8192;
  u16*   wcH    = whL + 8192;
  u16*   wcL    = wcH + 16384;
  size_t needed = (size_t)((char*)(wcL + 16384) - (char*)ws);
  if (ws_size < needed) return;

  prep_split<<<96, 256, 0, stream>>>(fc1w, cw, whH, whL, wcH, wcL);
  fc0_kernel<<<1024, 256, 0, stream>>>(x, fc0w, fc0b, v);

  for (int i = 0; i < 4; ++i) {
    dwt_big<<<BC * 4, 256, 0, stream>>>(v, highs, lo_f);
    dwt_small<<<BC, 256, 0, stream>>>(lo_f, highs, yl_raw);
    mix2<<<672, 256, 0, stream>>>(yl_raw, highs, w1 + (size_t)i * 64 * 64 * MODES,
                                  w2 + (size_t)i * 64 * 64 * MODES, yl_m, yh_m);
    idwt_small<<<BC, 256, 0, stream>>>(yl_m, yh_m, highs, lo_i);
    idwt_big<<<BC * 4, 256, 0, stream>>>(lo_i, highs, x1);
    pw_mfma<<<4096, 256, 0, stream>>>(x1, v, wcH + i * 4096, wcL + i * 4096, cb + i * 64, (i < 3) ? 1 : 0);
  }

  head_mfma<<<4096, 256, 0, stream>>>(v, whH, whL, fc1b, fc2w, fc2b, out);
}

// Round 9
// 584.578 us; speedup vs baseline: 3.1569x; 1.0437x over previous
//
#include <hip/hip_runtime.h>
#include <cmath>

#define BC 2048          // B*W sequences
#define S_LEN 8192
#define MODES 42
// padded pyramid: L1@0(4101) L2@4104(2056) L3@6160(1033) L4@7196(522)
//                 L5@7720(266) L6@7988(138) L7@8128(74) L8@8204(42)
#define HTOT 8248
#define LO_STR 1036      // padded stride for the 1033-long lo buffers

static constexpr float C_LO[12] = {
  0.11154074335008017f, 0.4946238903983854f, 0.7511339080215775f,
  0.3152503517092432f, -0.22626469396516913f, -0.12976686756709563f,
  0.09750160558707936f, 0.02752286553001629f, -0.031582039318031156f,
  0.0005538422009938016f, 0.004777257511010651f, -0.00107730108499558f };

__device__ __forceinline__ float rec_lo_c(int k){ return C_LO[k]; }
__device__ __forceinline__ float rec_hi_c(int k){ float v = C_LO[11-k]; return (k&1)? -v : v; }
__device__ __forceinline__ float dec_lo_c(int k){ return C_LO[11-k]; }
__device__ __forceinline__ float dec_hi_c(int k){ float v = C_LO[k];    return (k&1)?  v : -v; }

// branchless erf (Abramowitz-Stegun 7.1.26, |err|<=1.5e-7)
__device__ __forceinline__ float erf_fast(float x){
  float ax = fabsf(x);
  float t  = __fdividef(1.0f, 1.0f + 0.3275911f * ax);
  float p  = ((((1.061405429f * t - 1.453152027f) * t) + 1.421413741f) * t - 0.284496736f) * t + 0.254829592f;
  float y  = 1.0f - p * t * __expf(-ax * ax);
  return copysignf(y, x);
}
__device__ __forceinline__ float gelu_f(float x){
  return 0.5f * x * (1.0f + erf_fast(x * 0.70710678118654752440f));
}

__device__ __forceinline__ int reflect_i(int t, int n){
  t = (t < 0) ? (-1 - t) : t;
  t = (t >= n) ? (2 * n - 1 - t) : t;
  return t;
}

__device__ __forceinline__ unsigned short bf16_rn(float x){
  unsigned int b = __float_as_uint(x);
  b += 0x7FFF + ((b >> 16) & 1);
  return (unsigned short)(b >> 16);
}
__device__ __forceinline__ float bf16_to_f(unsigned short h){
  return __uint_as_float(((unsigned int)h) << 16);
}

typedef short  v8s __attribute__((ext_vector_type(8)));
typedef float  v4f __attribute__((ext_vector_type(4)));
typedef unsigned short u16;

__device__ __forceinline__ void ld3f4(float* w, const float* s){
  *(float4*)&w[0] = *(const float4*)&s[0];
  *(float4*)&w[4] = *(const float4*)&s[4];
  *(float4*)&w[8] = *(const float4*)&s[8];
}
__device__ __forceinline__ void ld5f4(float* w, const float* s){
  *(float4*)&w[0]  = *(const float4*)&s[0];
  *(float4*)&w[4]  = *(const float4*)&s[4];
  *(float4*)&w[8]  = *(const float4*)&s[8];
  *(float4*)&w[12] = *(const float4*)&s[12];
  *(float4*)&w[16] = *(const float4*)&s[16];
}
__device__ __forceinline__ void ld4f2(float* w, const float* s){
  *(float2*)&w[0] = *(const float2*)&s[0];
  *(float2*)&w[2] = *(const float2*)&s[2];
  *(float2*)&w[4] = *(const float2*)&s[4];
  *(float2*)&w[6] = *(const float2*)&s[6];
}

// zero-pad staging: dst[j] = (0<=g0+j<n) ? src[g0+j] : 0 ; g0%4==0, cnt%4==0
__device__ __forceinline__ void stage_g(float* dst, const float* src, int g0, int cnt, int n){
  for (int j4 = threadIdx.x; j4 < (cnt >> 2); j4 += 256) {
    int g = g0 + 4 * j4;
    float4 val;
    if (g >= 0 && g + 3 < n) val = *(const float4*)&src[g];
    else {
      val.x = (g   >= 0 && g   < n) ? src[g]   : 0.f;
      val.y = (g+1 >= 0 && g+1 < n) ? src[g+1] : 0.f;
      val.z = (g+2 >= 0 && g+2 < n) ? src[g+2] : 0.f;
      val.w = (g+3 >= 0 && g+3 < n) ? src[g+3] : 0.f;
    }
    *(float4*)&dst[4*j4] = val;
  }
}

__device__ __forceinline__ void stage_band4(float* dst, const float* src, int len, int alloc){
  for (int i4 = threadIdx.x; i4 < (alloc >> 2); i4 += 256) {
    int i = 4 * i4;
    float4 v;
    if (i + 3 < len) v = *(const float4*)&src[i];
    else {
      v.x = (i   < len) ? src[i]   : 0.f;
      v.y = (i+1 < len) ? src[i+1] : 0.f;
      v.z = (i+2 < len) ? src[i+2] : 0.f;
      v.w = (i+3 < len) ? src[i+3] : 0.f;
    }
    *(float4*)&dst[i] = v;
  }
}

// 4 IDWT outputs m=u0..u0+3 from windows wl/wh[8]; tap base SH + (d>>1)
template<int SH>
__device__ __forceinline__ void idwt4s(const float* wl, const float* wh, float* o4){
  #pragma unroll
  for (int d = 0; d < 4; ++d) {
    const int q = SH + (d >> 1);
    float acc = 0.f;
    if (d & 1) {
      #pragma unroll
      for (int i = 0; i < 6; ++i) acc += wl[q+i]*dec_lo_c(2*i)   + wh[q+i]*dec_hi_c(2*i);
    } else {
      #pragma unroll
      for (int i = 0; i < 6; ++i) acc += wl[q+i]*dec_lo_c(2*i+1) + wh[q+i]*dec_hi_c(2*i+1);
    }
    o4[d] = acc;
  }
}

// ---------------------------------------------------------------- prep: split weights to hi/lo bf16 in swizzled layout
__global__ __launch_bounds__(256) void prep_split(
    const float* __restrict__ fc1w, const float* __restrict__ cw,
    u16* __restrict__ whH, u16* __restrict__ whL,
    u16* __restrict__ wcH, u16* __restrict__ wcL)
{
  int i = blockIdx.x * 256 + threadIdx.x;
  if (i < 8192) {
    int c = i >> 7, j = i & 127;
    float wv = fc1w[i];
    u16 h = bf16_rn(wv);
    float lo = wv - bf16_to_f(h);
    int cs = c ^ ((j & 7) << 3);
    whH[j * 64 + cs] = h; whL[j * 64 + cs] = bf16_rn(lo);
  }
  int k = i - 8192;
  if (k >= 0 && k < 16384) {
    int l = k >> 12, r = k & 4095;
    int c = r >> 6, o = r & 63;
    float wv = cw[k];
    u16 h = bf16_rn(wv);
    float lo = wv - bf16_to_f(h);
    int cs = c ^ ((o & 7) << 3);
    wcH[l * 4096 + o * 64 + cs] = h; wcL[l * 4096 + o * 64 + cs] = bf16_rn(lo);
  }
}

// ---------------------------------------------------------------- fc0
__global__ __launch_bounds__(256) void fc0_kernel(
    const float* __restrict__ x, const float* __restrict__ w,
    const float* __restrict__ bias, float* __restrict__ v)
{
  int p = blockIdx.x * 256 + threadIdx.x;
  int b = p >> 13, s = p & 8191;
  float xv = x[p];
  float g  = (float)s * (1.0f / 8191.0f);
  for (int c = 0; c < 64; ++c) {
    v[((size_t)(b * 64 + c)) * S_LEN + s] = xv * w[c] + g * w[64 + c] + bias[c];
  }
}

// ---------------------------------------------------------------- DWT big: 8192->4101->2056->1033, 4 chunks/seq
// polyphase storage (E=even, O=odd combined index) for conflict-free b128 reads
__global__ __launch_bounds__(256) void dwt_big(
    const float* __restrict__ vin, float* __restrict__ highs, float* __restrict__ lo_f)
{
  __shared__ alignas(16) float sVE[1096], sVO[1096];
  __shared__ alignas(16) float sL1Eb[548], sL1Ob[548];   // +4 front pad
  __shared__ alignas(16) float sL2E[276], sL2O[276];
  float* sL1E = sL1Eb + 4;
  float* sL1O = sL1Ob + 4;

  int seq = blockIdx.x >> 2, c = blockIdx.x & 3;
  const float* src = vin + (size_t)seq * S_LEN;
  float* hseq = highs + (size_t)seq * HTOT;
  int tid = threadIdx.x;

  // stage: sVE[j]=src[reflect(g0+2j)], sVO[j]=src[reflect(g0+2j+1)], g0=2080c-76, 2180 floats
  int g0 = 2080 * c - 76;
  for (int j4 = tid; j4 < 545; j4 += 256) {
    int g = g0 + 4 * j4;
    float4 val;
    if (g >= 0 && g + 3 < 8192) val = *(const float4*)&src[g];
    else {
      val.x = src[reflect_i(g,   8192)];
      val.y = src[reflect_i(g+1, 8192)];
      val.z = src[reflect_i(g+2, 8192)];
      val.w = src[reflect_i(g+3, 8192)];
    }
    *(float2*)&sVE[2*j4] = make_float2(val.x, val.z);
    *(float2*)&sVO[2*j4] = make_float2(val.y, val.w);
  }
  __syncthreads();

  // ---- L1: u' in [0,1084), m1 = (1040c-32)+u'. taps: E[u'+1+j]*rl(2j) + O[u'+1+j]*rl(2j+1)
  {
    int base1m = 1040 * c - 32;
    int uh1 = (c < 3) ? 1072 : 1013;
    for (int u0 = 4 * tid; u0 < 1084; u0 += 1024) {
      float we[12], wo[12];
      ld3f4(we, &sVE[u0]); ld3f4(wo, &sVO[u0]);
      float lo4[4], hi4[4];
      #pragma unroll
      for (int d = 0; d < 4; ++d) {
        float alo = 0.f, ahi = 0.f;
        #pragma unroll
        for (int j = 0; j < 6; ++j) {
          float e = we[d+1+j], oo = wo[d+1+j];
          alo += e * rec_lo_c(2*j) + oo * rec_lo_c(2*j+1);
          ahi += e * rec_hi_c(2*j) + oo * rec_hi_c(2*j+1);
        }
        lo4[d] = alo; hi4[d] = ahi;
      }
      *(float2*)&sL1E[u0 >> 1] = make_float2(lo4[0], lo4[2]);
      *(float2*)&sL1O[u0 >> 1] = make_float2(lo4[1], lo4[3]);
      if (u0 >= 32 && u0 + 3 < uh1) {
        *(float4*)&hseq[base1m + u0] = make_float4(hi4[0], hi4[1], hi4[2], hi4[3]);
      } else {
        #pragma unroll
        for (int d = 0; d < 4; ++d) {
          int u = u0 + d;
          if (u >= 32 && u < uh1) hseq[base1m + u] = hi4[d];
        }
      }
    }
  }
  __syncthreads();
  // L1 edge fixups (combined index): c0: u<32 <- 63-u ; c3: u in [1013,1084) <- 2025-u
  if (c == 0) {
    for (int u = tid; u < 32; u += 256) {
      int j = 63 - u;
      float v = (j & 1) ? sL1O[j >> 1] : sL1E[j >> 1];
      if (u & 1) sL1O[u >> 1] = v; else sL1E[u >> 1] = v;
    }
  }
  if (c == 3) {
    for (int u = 1013 + tid; u < 1084; u += 256) {
      int j = 2025 - u;
      float v = (j & 1) ? sL1O[j >> 1] : sL1E[j >> 1];
      if (u & 1) sL1O[u >> 1] = v; else sL1E[u >> 1] = v;
    }
  }
  __syncthreads();

  // ---- L2: u2' in [0,536), m2 = (520c-12)+u2'. taps: E1[u2'-1+j] -> we[d+3+j] (load base u0-4)
  {
    int base2m = 520 * c - 12;
    int uh2 = (c < 3) ? 532 : 508;
    for (int u0 = 4 * tid; u0 < 536; u0 += 1024) {
      float we[12], wo[12];
      ld3f4(we, &sL1E[u0 - 4]); ld3f4(wo, &sL1O[u0 - 4]);
      float lo4[4], hi4[4];
      #pragma unroll
      for (int d = 0; d < 4; ++d) {
        float alo = 0.f, ahi = 0.f;
        #pragma unroll
        for (int j = 0; j < 6; ++j) {
          float e = we[d+3+j], oo = wo[d+3+j];
          alo += e * rec_lo_c(2*j) + oo * rec_lo_c(2*j+1);
          ahi += e * rec_hi_c(2*j) + oo * rec_hi_c(2*j+1);
        }
        lo4[d] = alo; hi4[d] = ahi;
      }
      *(float2*)&sL2E[u0 >> 1] = make_float2(lo4[0], lo4[2]);
      *(float2*)&sL2O[u0 >> 1] = make_float2(lo4[1], lo4[3]);
      if (u0 >= 12 && u0 < uh2)
        *(float4*)&hseq[4104 + base2m + u0] = make_float4(hi4[0], hi4[1], hi4[2], hi4[3]);
    }
  }
  __syncthreads();
  // L2 fixups: c0: u<12 <- 23-u ; c3: u in [508,536) <- 1015-u
  if (c == 0) {
    for (int u = tid; u < 12; u += 256) {
      int j = 23 - u;
      float v = (j & 1) ? sL2O[j >> 1] : sL2E[j >> 1];
      if (u & 1) sL2O[u >> 1] = v; else sL2E[u >> 1] = v;
    }
  }
  if (c == 3) {
    for (int u = 508 + tid; u < 536; u += 256) {
      int j = 1015 - u;
      float v = (j & 1) ? sL2O[j >> 1] : sL2E[j >> 1];
      if (u & 1) sL2O[u >> 1] = v; else sL2E[u >> 1] = v;
    }
  }
  __syncthreads();

  // ---- L3: u3 in [0,260), m3 = 260c+u3. taps: E2[u3+1+j]
  for (int u0 = 4 * tid; u0 < 260; u0 += 1024) {
    float we[12], wo[12];
    ld3f4(we, &sL2E[u0]); ld3f4(wo, &sL2O[u0]);
    float lo4[4], hi4[4];
    #pragma unroll
    for (int d = 0; d < 4; ++d) {
      float alo = 0.f, ahi = 0.f;
      #pragma unroll
      for (int j = 0; j < 6; ++j) {
        float e = we[d+1+j], oo = wo[d+1+j];
        alo += e * rec_lo_c(2*j) + oo * rec_lo_c(2*j+1);
        ahi += e * rec_hi_c(2*j) + oo * rec_hi_c(2*j+1);
      }
      lo4[d] = alo; hi4[d] = ahi;
    }
    int m0 = 260 * c + u0;
    if (m0 + 3 < 1033) {
      *(float4*)&lo_f[(size_t)seq * LO_STR + m0] = make_float4(lo4[0], lo4[1], lo4[2], lo4[3]);
      *(float4*)&hseq[6160 + m0] = make_float4(hi4[0], hi4[1], hi4[2], hi4[3]);
    } else {
      #pragma unroll
      for (int d = 0; d < 4; ++d) {
        int m = m0 + d;
        if (m < 1033 && u0 + d < 260) {
          lo_f[(size_t)seq * LO_STR + m] = lo4[d];
          hseq[6160 + m] = hi4[d];
        }
      }
    }
  }
}

// ---------------------------------------------------------------- DWT small: 1033->522->266->138->74->42 per seq
__device__ __forceinline__ void dwt_lvl_v(const float* in, int n, float* out, int outn, float* hg)
{
  for (int u0 = 4*(int)threadIdx.x; u0 < outn; u0 += 1024) {
    bool fast = (u0 >= 8) && (2*u0 + 7 < n) && (u0 + 3 < outn);
    if (fast) {
      float w[20];
      ld5f4(w, &in[2*u0 - 12]);
      #pragma unroll
      for (int d = 0; d < 4; ++d) {
        float alo = 0.f, ahi = 0.f;
        #pragma unroll
        for (int k = 0; k < 12; ++k) {
          float x = w[2*d + 2 + k];
          alo += x * rec_lo_c(k); ahi += x * rec_hi_c(k);
        }
        out[u0+d] = alo; hg[u0+d] = ahi;
      }
    } else {
      for (int d = 0; d < 4; ++d) {
        if (u0 + d < outn) {
          float alo = 0.f, ahi = 0.f;
          #pragma unroll
          for (int k = 0; k < 12; ++k) {
            float x = in[reflect_i(2*(u0+d) + k - 10, n)];
            alo += x * rec_lo_c(k); ahi += x * rec_hi_c(k);
          }
          out[u0+d] = alo; hg[u0+d] = ahi;
        }
      }
    }
  }
  __syncthreads();
}

__global__ __launch_bounds__(256) void dwt_small(
    const float* __restrict__ lo_f, float* __restrict__ highs, float* __restrict__ yl)
{
  __shared__ alignas(16) float A[1040], Bb[528];
  int seq = blockIdx.x;
  const float* src = lo_f + (size_t)seq * LO_STR;
  float* hseq = highs + (size_t)seq * HTOT;
  for (int i = 4*(int)threadIdx.x; i < 1033; i += 1024) {
    if (i + 3 < 1033) *(float4*)&A[i] = *(const float4*)&src[i];
    else { for (int d = 0; d < 4; ++d) if (i + d < 1033) A[i+d] = src[i+d]; }
  }
  __syncthreads();
  dwt_lvl_v(A, 1033, Bb, 522, hseq + 7196);
  dwt_lvl_v(Bb, 522, A, 266, hseq + 7720);
  dwt_lvl_v(A, 266, Bb, 138, hseq + 7988);
  dwt_lvl_v(Bb, 138, A, 74,  hseq + 8128);
  dwt_lvl_v(A, 74,  Bb, 42,  hseq + 8204);
  for (int m = threadIdx.x; m < MODES; m += 256) yl[seq * MODES + m] = Bb[m];
}

// ---------------------------------------------------------------- IDWT small + fused channel mix
// block = seq = b*64+o. prologue computes yl_m/yh_m rows (the old mix42) directly into LDS.
__device__ __forceinline__ void idwt_lvl4(const float* lo, const float* h, float* out, int outn)
{
  for (int u0 = 4*(int)threadIdx.x; u0 < outn; u0 += 1024) {
    int q = u0 >> 1;
    float wl[8], wh[8];
    ld4f2(wl, &lo[q]); ld4f2(wh, &h[q]);
    float o4[4]; idwt4s<0>(wl, wh, o4);
    if (u0 + 3 < outn) *(float4*)&out[u0] = make_float4(o4[0], o4[1], o4[2], o4[3]);
    else { for (int d = 0; d < 4; ++d) if (u0 + d < outn) out[u0+d] = o4[d]; }
  }
  __syncthreads();
}

__global__ __launch_bounds__(256) void idwt_small(
    const float* __restrict__ yl_raw, const float* __restrict__ highs,
    const float* __restrict__ w1l, const float* __restrict__ w2l,
    float* __restrict__ lo_i)
{
  // bands: yl@0(48) yh@48(48) h74@96(80) h138@176(144) h266@320(272) h522@592(528)
  __shared__ alignas(16) float bands[1120], wa[272], wb[528];
  int seq = blockIdx.x;
  int b = seq >> 6, o = seq & 63;
  const float* hseq = highs + (size_t)seq * HTOT;
  int t = threadIdx.x;

  stage_band4(bands + 96,  hseq + 8128, 74, 80);
  stage_band4(bands + 176, hseq + 7988, 138, 144);
  stage_band4(bands + 320, hseq + 7720, 266, 272);
  stage_band4(bands + 592, hseq + 7196, 522, 528);

  if (t >= 42 && t < 48) { bands[t] = 0.f; bands[48 + t] = 0.f; }
  if (t < 42) {
    const float* yr = yl_raw + (size_t)b * 2688 + t;                 // + i*42
    const float* hh = highs + (size_t)(b * 64) * HTOT + 8204 + t;    // + i*HTOT
    const float* wl = w1l + o * 42 + t;                               // + i*2688
    const float* wh = w2l + o * 42 + t;
    float accl = 0.f, acch = 0.f;
    #pragma unroll 4
    for (int i = 0; i < 64; ++i) {
      accl += yr[i * 42] * wl[i * 2688];
      acch += hh[(size_t)i * HTOT] * wh[i * 2688];
    }
    bands[t] = accl; bands[48 + t] = acch;
  }
  __syncthreads();

  idwt_lvl4(bands + 0,   bands + 48,  wa, 74);
  idwt_lvl4(wa,          bands + 96,  wb, 138);
  idwt_lvl4(wb,          bands + 176, wa, 266);
  idwt_lvl4(wa,          bands + 320, wb, 522);

  for (int u0 = 4 * t; u0 < 1033; u0 += 1024) {
    int q = u0 >> 1;
    float wl[8], wh[8];
    ld4f2(wl, &wb[q]); ld4f2(wh, &bands[592 + q]);
    float o4[4]; idwt4s<0>(wl, wh, o4);
    float* dst = lo_i + (size_t)seq * LO_STR + u0;
    if (u0 + 3 < 1033) *(float4*)&dst[0] = make_float4(o4[0], o4[1], o4[2], o4[3]);
    else { for (int d = 0; d < 4; ++d) if (u0 + d < 1033) dst[d] = o4[d]; }
  }
}

// ---------------------------------------------------------------- IDWT big: 1033->2056->4101->8192, 4 chunks/seq
__global__ __launch_bounds__(256) void idwt_big(
    const float* __restrict__ lo_i, const float* __restrict__ highs, float* __restrict__ x1)
{
  __shared__ alignas(16) float sL3[288], sH3[288], sL2[544], sH2[544], sL1[1048], sH1[1048];
  int seq = blockIdx.x >> 2, c = blockIdx.x & 3;
  const float* hseq = highs + (size_t)seq * HTOT;
  const float* l3   = lo_i + (size_t)seq * LO_STR;
  int g3 = 256*c - 4, g2 = 512*c - 4, g1 = 1024*c - 4;
  int t = threadIdx.x;

  stage_g(sL3, l3,          g3, 288, 1033);
  stage_g(sH3, hseq + 6160, g3, 288, 1033);
  stage_g(sH2, hseq + 4104, g2, 544, 2056);
  stage_g(sH1, hseq,        g1, 1048, 4101);
  __syncthreads();

  // s5: m = (512c-2)+u, u in [0,536); window idx = (u>>1)+(d>>1)+3 -> load base q+2, SH=1
  for (int u0 = 4 * t; u0 < 536; u0 += 1024) {
    int q = u0 >> 1;
    float wl[8], wh[8];
    ld4f2(wl, &sL3[q + 2]); ld4f2(wh, &sH3[q + 2]);
    float o4[4]; idwt4s<1>(wl, wh, o4);
    #pragma unroll
    for (int d = 0; d < 4; ++d) {
      int m = 512*c - 2 + u0 + d;
      o4[d] = (m >= 0 && m < 2056) ? o4[d] : 0.f;
    }
    *(float2*)&sL2[u0 + 2] = make_float2(o4[0], o4[1]);
    *(float2*)&sL2[u0 + 4] = make_float2(o4[2], o4[3]);
  }
  __syncthreads();

  // s6: m = (1024c-2)+u, u in [0,1040); same SH=1 structure
  for (int u0 = 4 * t; u0 < 1040; u0 += 1024) {
    int q = u0 >> 1;
    float wl[8], wh[8];
    ld4f2(wl, &sL2[q + 2]); ld4f2(wh, &sH2[q + 2]);
    float o4[4]; idwt4s<1>(wl, wh, o4);
    #pragma unroll
    for (int d = 0; d < 4; ++d) {
      int m = 1024*c - 2 + u0 + d;
      o4[d] = (m >= 0 && m < 4101) ? o4[d] : 0.f;
    }
    *(float2*)&sL1[u0 + 2] = make_float2(o4[0], o4[1]);
    *(float2*)&sL1[u0 + 4] = make_float2(o4[2], o4[3]);
  }
  __syncthreads();

  // s7: m = 2048c+u, u in [0,2048); window idx = (u>>1)+(d>>1)+4 -> load base q+4, SH=0
  for (int u0 = 4 * t; u0 < 2048; u0 += 1024) {
    int q = u0 >> 1;
    float wl[8], wh[8];
    ld4f2(wl, &sL1[q + 4]); ld4f2(wh, &sH1[q + 4]);
    float o4[4]; idwt4s<0>(wl, wh, o4);
    *(float4*)&x1[(size_t)seq * S_LEN + 2048*c + u0] = make_float4(o4[0], o4[1], o4[2], o4[3]);
  }
}

// ---------------------------------------------------------------- layer pointwise via MFMA (split bf16, pre-split W)
__global__ __launch_bounds__(256) void pw_mfma(
    const float* __restrict__ x1, float* v,
    const u16* __restrict__ wcH, const u16* __restrict__ wcL,
    const float* __restrict__ cb, int do_gelu)
{
  __shared__ u16 aH[64][64], aL[64][64];
  __shared__ u16 wH[64][64], wL[64][64];
  __shared__ float cbl[64];
  int b  = blockIdx.x >> 7;
  int s0 = (blockIdx.x & 127) << 6;
  int t  = threadIdx.x;

  {
    const v8s* srcH = (const v8s*)wcH;
    const v8s* srcL = (const v8s*)wcL;
    v8s* dstH = (v8s*)&wH[0][0];
    v8s* dstL = (v8s*)&wL[0][0];
    #pragma unroll
    for (int r = 0; r < 2; ++r) {
      dstH[t + 256 * r] = srcH[t + 256 * r];
      dstL[t + 256 * r] = srcL[t + 256 * r];
    }
  }
  if (t < 64) cbl[t] = cb[t];

  #pragma unroll
  for (int r = 0; r < 4; ++r) {
    int idx = t + 256 * r;
    int ch = idx >> 4, p4 = (idx & 15) << 2;
    float4 xv = *(const float4*)&v[((size_t)(b * 64 + ch)) * S_LEN + s0 + p4];
    u16 h0 = bf16_rn(xv.x); aH[p4+0][ch ^ (((p4+0)&7)<<3)] = h0; aL[p4+0][ch ^ (((p4+0)&7)<<3)] = bf16_rn(xv.x - bf16_to_f(h0));
    u16 h1 = bf16_rn(xv.y); aH[p4+1][ch ^ (((p4+1)&7)<<3)] = h1; aL[p4+1][ch ^ (((p4+1)&7)<<3)] = bf16_rn(xv.y - bf16_to_f(h1));
    u16 h2 = bf16_rn(xv.z); aH[p4+2][ch ^ (((p4+2)&7)<<3)] = h2; aL[p4+2][ch ^ (((p4+2)&7)<<3)] = bf16_rn(xv.z - bf16_to_f(h2));
    u16 h3 = bf16_rn(xv.w); aH[p4+3][ch ^ (((p4+3)&7)<<3)] = h3; aL[p4+3][ch ^ (((p4+3)&7)<<3)] = bf16_rn(xv.w - bf16_to_f(h3));
  }
  __syncthreads();

  int l = t & 63, wv_ = t >> 6;
  int pi = l & 15, kg = l >> 4;
  int pos = wv_ * 16 + pi;
  int swz = (pi & 7) << 3;

  v4f acc[4];
  #pragma unroll
  for (int i = 0; i < 4; ++i) acc[i] = v4f{0.f, 0.f, 0.f, 0.f};

  #pragma unroll
  for (int kt = 0; kt < 2; ++kt) {
    int ka = (kg * 8 + kt * 32) ^ swz;
    v8s ah = *(const v8s*)&aH[pos][ka];
    v8s al = *(const v8s*)&aL[pos][ka];
    #pragma unroll
    for (int ct = 0; ct < 4; ++ct) {
      int o = ct * 16 + pi;
      v8s bh = *(const v8s*)&wH[o][ka];
      v8s bl = *(const v8s*)&wL[o][ka];
      acc[ct] = __builtin_amdgcn_mfma_f32_16x16x32_bf16(ah, bh, acc[ct], 0, 0, 0);
      acc[ct] = __builtin_amdgcn_mfma_f32_16x16x32_bf16(ah, bl, acc[ct], 0, 0, 0);
      acc[ct] = __builtin_amdgcn_mfma_f32_16x16x32_bf16(al, bh, acc[ct], 0, 0, 0);
    }
  }

  #pragma unroll
  for (int ct = 0; ct < 4; ++ct) {
    int o = ct * 16 + pi;
    size_t base = ((size_t)(b * 64 + o)) * S_LEN + s0 + wv_ * 16 + kg * 4;
    float4 x4 = *(const float4*)&x1[base];
    float cbv = cbl[o];
    float y0 = acc[ct][0] + x4.x + cbv;
    float y1 = acc[ct][1] + x4.y + cbv;
    float y2 = acc[ct][2] + x4.z + cbv;
    float y3 = acc[ct][3] + x4.w + cbv;
    if (do_gelu) { y0 = gelu_f(y0); y1 = gelu_f(y1); y2 = gelu_f(y2); y3 = gelu_f(y3); }
    float4 y4 = make_float4(y0, y1, y2, y3);
    *(float4*)&v[base] = y4;
  }
}

// ---------------------------------------------------------------- head via MFMA (pre-split W)
__global__ __launch_bounds__(256) void head_mfma(
    const float* __restrict__ v,
    const u16* __restrict__ whH, const u16* __restrict__ whL,
    const float* __restrict__ fc1b, const float* __restrict__ fc2w,
    const float* __restrict__ fc2b, float* __restrict__ out)
{
  __shared__ u16 aH[64][64], aL[64][64];
  __shared__ u16 wH[128][64], wL[128][64];
  __shared__ float f1b[128], f2w[128];
  int b  = blockIdx.x >> 7;
  int s0 = (blockIdx.x & 127) << 6;
  int t  = threadIdx.x;

  {
    const v8s* srcH = (const v8s*)whH;
    const v8s* srcL = (const v8s*)whL;
    v8s* dstH = (v8s*)&wH[0][0];
    v8s* dstL = (v8s*)&wL[0][0];
    #pragma unroll
    for (int r = 0; r < 4; ++r) {
      dstH[t + 256 * r] = srcH[t + 256 * r];
      dstL[t + 256 * r] = srcL[t + 256 * r];
    }
  }
  if (t < 128) { f1b[t] = fc1b[t]; f2w[t] = fc2w[t]; }

  #pragma unroll
  for (int r = 0; r < 4; ++r) {
    int idx = t + 256 * r;
    int ch = idx >> 4, p4 = (idx & 15) << 2;
    float4 xv = *(const float4*)&v[((size_t)(b * 64 + ch)) * S_LEN + s0 + p4];
    u16 h0 = bf16_rn(xv.x); aH[p4+0][ch ^ (((p4+0)&7)<<3)] = h0; aL[p4+0][ch ^ (((p4+0)&7)<<3)] = bf16_rn(xv.x - bf16_to_f(h0));
    u16 h1 = bf16_rn(xv.y); aH[p4+1][ch ^ (((p4+1)&7)<<3)] = h1; aL[p4+1][ch ^ (((p4+1)&7)<<3)] = bf16_rn(xv.y - bf16_to_f(h1));
    u16 h2 = bf16_rn(xv.z); aH[p4+2][ch ^ (((p4+2)&7)<<3)] = h2; aL[p4+2][ch ^ (((p4+2)&7)<<3)] = bf16_rn(xv.z - bf16_to_f(h2));
    u16 h3 = bf16_rn(xv.w); aH[p4+3][ch ^ (((p4+3)&7)<<3)] = h3; aL[p4+3][ch ^ (((p4+3)&7)<<3)] = bf16_rn(xv.w - bf16_to_f(h3));
  }
  __syncthreads();

  int l = t & 63, wv_ = t >> 6;
  int pi = l & 15, kg = l >> 4;
  int pos = wv_ * 16 + pi;
  int swz = (pi & 7) << 3;

  v4f acc[8];
  #pragma unroll
  for (int i = 0; i < 8; ++i) acc[i] = v4f{0.f, 0.f, 0.f, 0.f};

  #pragma unroll
  for (int kt = 0; kt < 2; ++kt) {
    int ka = (kg * 8 + kt * 32) ^ swz;
    v8s ah = *(const v8s*)&aH[pos][ka];
    v8s al = *(const v8s*)&aL[pos][ka];
    #pragma unroll
    for (int ct = 0; ct < 8; ++ct) {
      int j = ct * 16 + pi;
      v8s bh = *(const v8s*)&wH[j][ka];
      v8s bl = *(const v8s*)&wL[j][ka];
      acc[ct] = __builtin_amdgcn_mfma_f32_16x16x32_bf16(ah, bh, acc[ct], 0, 0, 0);
      acc[ct] = __builtin_amdgcn_mfma_f32_16x16x32_bf16(ah, bl, acc[ct], 0, 0, 0);
      acc[ct] = __builtin_amdgcn_mfma_f32_16x16x32_bf16(al, bh, acc[ct], 0, 0, 0);
    }
  }

  float part[4] = {0.f, 0.f, 0.f, 0.f};
  #pragma unroll
  for (int ct = 0; ct < 8; ++ct) {
    int j = ct * 16 + pi;
    float bias = f1b[j], f2 = f2w[j];
    #pragma unroll
    for (int r = 0; r < 4; ++r) {
      float d = acc[ct][r] + bias;
      part[r] += f2 * gelu_f(d);
    }
  }
  #pragma unroll
  for (int r = 0; r < 4; ++r) {
    part[r] += __shfl_xor(part[r], 1, 16);
    part[r] += __shfl_xor(part[r], 2, 16);
    part[r] += __shfl_xor(part[r], 4, 16);
    part[r] += __shfl_xor(part[r], 8, 16);
  }
  if (pi == 0) {
    float b2 = fc2b[0];
    float4 o4 = make_float4(part[0] + b2, part[1] + b2, part[2] + b2, part[3] + b2);
    *(float4*)&out[(size_t)b * S_LEN + s0 + wv_ * 16 + kg * 4] = o4;
  }
}

// ----------------------------------------------------------------
extern "C" void kernel_launch(void* const* d_in, const int* in_sizes, int n_in,
                              void* d_out, int out_size, void* d_ws, size_t ws_size,
                              hipStream_t stream) {
  const float* x    = (const float*)d_in[0];
  const float* fc0w = (const float*)d_in[1];
  const float* fc0b = (const float*)d_in[2];
  const float* w1   = (const float*)d_in[3];
  const float* w2   = (const float*)d_in[4];
  const float* cw   = (const float*)d_in[5];
  const float* cb   = (const float*)d_in[6];
  const float* fc1w = (const float*)d_in[7];
  const float* fc1b = (const float*)d_in[8];
  const float* fc2w = (const float*)d_in[9];
  const float* fc2b = (const float*)d_in[10];
  float* out = (float*)d_out;

  float* ws     = (float*)d_ws;
  float* v      = ws;
  float* x1     = v      + (size_t)BC * S_LEN;
  float* highs  = x1     + (size_t)BC * S_LEN;
  float* yl_raw = highs  + (size_t)BC * HTOT;
  float* lo_f   = yl_raw + (size_t)BC * MODES;
  float* lo_i   = lo_f   + (size_t)BC * LO_STR;
  u16*   whH    = (u16*)(lo_i + (size_t)BC * LO_STR);
  u16*   whL    = whH + 8192;
  u16*   wcH    = whL + 8192;
  u16*   wcL    = wcH + 16384;
  size_t needed = (size_t)((char*)(wcL + 16384) - (char*)ws);
  if (ws_size < needed) return;

  prep_split<<<96, 256, 0, stream>>>(fc1w, cw, whH, whL, wcH, wcL);
  fc0_kernel<<<1024, 256, 0, stream>>>(x, fc0w, fc0b, v);

  for (int i = 0; i < 4; ++i) {
    const float* w1l = w1 + (size_t)i * 64 * 64 * MODES;
    const float* w2l = w2 + (size_t)i * 64 * 64 * MODES;
    dwt_big<<<BC * 4, 256, 0, stream>>>(v, highs, lo_f);
    dwt_small<<<BC, 256, 0, stream>>>(lo_f, highs, yl_raw);
    idwt_small<<<BC, 256, 0, stream>>>(yl_raw, highs, w1l, w2l, lo_i);
    idwt_big<<<BC * 4, 256, 0, stream>>>(lo_i, highs, x1);
    pw_mfma<<<4096, 256, 0, stream>>>(x1, v, wcH + i * 4096, wcL + i * 4096, cb + i * 64, (i < 3) ? 1 : 0);
  }

  head_mfma<<<4096, 256, 0, stream>>>(v, whH, whL, fc1b, fc2w, fc2b, out);
}